// Round 10
// baseline (7001.888 us; speedup 1.0000x reference)
//
#include <hip/hip_runtime.h>
#include <cstddef>

constexpr int kB = 2;
constexpr int kN = 16384;
constexpr int kC = 64;
constexpr int kS = 4096;    // NPOINT
constexpr int kNS = 32;     // NSAMPLE
constexpr int kNC16 = 1024; // 16-point chunks per batch

typedef float f32x2 __attribute__((ext_vector_type(2)));
typedef float f32x4 __attribute__((ext_vector_type(4)));

__device__ __forceinline__ unsigned expand10(unsigned v) {
  v &= 1023u;
  v = (v | (v << 16)) & 0x030000FFu;
  v = (v | (v <<  8)) & 0x0300F00Fu;
  v = (v | (v <<  4)) & 0x030C30C3u;
  v = (v | (v <<  2)) & 0x09249249u;
  return v;
}

template <int C>
__device__ __forceinline__ unsigned dpp_u32(unsigned x) {
  return (unsigned)__builtin_amdgcn_update_dpp((int)x, (int)x, C, 0xF, 0xF, false);
}
// max over each aligned 4-lane quad (2 steps)
__device__ __forceinline__ unsigned max4(unsigned x) {
  x = max(x, dpp_u32<0xB1>(x));   // quad_perm [1,0,3,2]
  x = max(x, dpp_u32<0x4E>(x));   // quad_perm [2,3,0,1]
  return x;
}
// one u64-max DPP step on an (hi,lo) pair
template <int C>
__device__ __forceinline__ void u64max_dpp(unsigned& hi, unsigned& lo) {
  unsigned h2 = dpp_u32<C>(hi), l2 = dpp_u32<C>(lo);
  bool g = (h2 > hi) || (h2 == hi && l2 > lo);
  hi = g ? h2 : hi;
  lo = g ? l2 : lo;
}

#define PK_ADD(d, a, b) asm("v_pk_add_f32 %0, %1, %2" : "=v"(d) : "v"(a), "v"(b))
#define PK_MUL(d, a, b) asm("v_pk_mul_f32 %0, %1, %2" : "=v"(d) : "v"(a), "v"(b))

// -------- transpose [b][Cdim][Ndim] -> [b][Ndim][Cdim], 32x32 tiles --------
__global__ void transpose_kernel(const float* __restrict__ in,
                                 float* __restrict__ out,
                                 int Cdim, int Ndim) {
  __shared__ float tile[32][33];
  int b = blockIdx.z;
  int n0 = blockIdx.x * 32;
  int c0 = blockIdx.y * 32;
  int tx = threadIdx.x;
  const float* inb = in + (size_t)b * Cdim * Ndim;
  float* outb = out + (size_t)b * Cdim * Ndim;
#pragma unroll
  for (int i = threadIdx.y; i < 32; i += 8)
    tile[i][tx] = inb[(size_t)(c0 + i) * Ndim + (n0 + tx)];
  __syncthreads();
#pragma unroll
  for (int i = threadIdx.y; i < 32; i += 8)
    outb[(size_t)(n0 + i) * Cdim + (c0 + tx)] = tile[tx][i];
}

// -------- FPS prep: bbox -> morton -> in-LDS bitonic sort -> quad-SoA planes
// + 16-pt chunk AABB metadata. Sort/meta quality only affects SPEED, never
// correctness (any bijection + conservative AABB is exact).
// Quad layout: lane q (0..3) of chunk c owns sorted points c*16 + q + 4*slot,
// slot=0..3, stored as float4 at plane entry (c*4+q).
__global__ __launch_bounds__(1024) void fps_prep_kernel(
    const float* __restrict__ xyz, float* __restrict__ px4,
    float* __restrict__ py4, float* __restrict__ pz4,
    unsigned* __restrict__ po4, float* __restrict__ aabb) {
  const int b = blockIdx.x;
  const int t = threadIdx.x;
  const int lane = t & 63;
  const int w = t >> 6;
  const float* P = xyz + (size_t)b * kN * 3;
  __shared__ unsigned long long keys[kN];   // 128 KB
  __shared__ float sbb[6][16];

  float mnx = 3e38f, mny = 3e38f, mnz = 3e38f;
  float mxx = -3e38f, mxy = -3e38f, mxz = -3e38f;
  for (int p = t; p < kN; p += 1024) {
    float x = P[p * 3], y = P[p * 3 + 1], z = P[p * 3 + 2];
    mnx = fminf(mnx, x); mny = fminf(mny, y); mnz = fminf(mnz, z);
    mxx = fmaxf(mxx, x); mxy = fmaxf(mxy, y); mxz = fmaxf(mxz, z);
  }
#pragma unroll
  for (int off = 32; off >= 1; off >>= 1) {
    mnx = fminf(mnx, __shfl_xor(mnx, off, 64));
    mny = fminf(mny, __shfl_xor(mny, off, 64));
    mnz = fminf(mnz, __shfl_xor(mnz, off, 64));
    mxx = fmaxf(mxx, __shfl_xor(mxx, off, 64));
    mxy = fmaxf(mxy, __shfl_xor(mxy, off, 64));
    mxz = fmaxf(mxz, __shfl_xor(mxz, off, 64));
  }
  if (lane == 0) {
    sbb[0][w] = mnx; sbb[1][w] = mny; sbb[2][w] = mnz;
    sbb[3][w] = mxx; sbb[4][w] = mxy; sbb[5][w] = mxz;
  }
  __syncthreads();
  mnx = sbb[0][lane & 15]; mny = sbb[1][lane & 15]; mnz = sbb[2][lane & 15];
  mxx = sbb[3][lane & 15]; mxy = sbb[4][lane & 15]; mxz = sbb[5][lane & 15];
#pragma unroll
  for (int off = 8; off >= 1; off >>= 1) {
    mnx = fminf(mnx, __shfl_xor(mnx, off, 64));
    mny = fminf(mny, __shfl_xor(mny, off, 64));
    mnz = fminf(mnz, __shfl_xor(mnz, off, 64));
    mxx = fmaxf(mxx, __shfl_xor(mxx, off, 64));
    mxy = fmaxf(mxy, __shfl_xor(mxy, off, 64));
    mxz = fmaxf(mxz, __shfl_xor(mxz, off, 64));
  }
  __syncthreads();
  const float sx = 1023.0f / fmaxf(mxx - mnx, 1e-20f);
  const float sy = 1023.0f / fmaxf(mxy - mny, 1e-20f);
  const float sz = 1023.0f / fmaxf(mxz - mnz, 1e-20f);
  for (int p = t; p < kN; p += 1024) {
    float x = P[p * 3], y = P[p * 3 + 1], z = P[p * 3 + 2];
    int qx = (int)((x - mnx) * sx); qx = max(0, min(1023, qx));
    int qy = (int)((y - mny) * sy); qy = max(0, min(1023, qy));
    int qz = (int)((z - mnz) * sz); qz = max(0, min(1023, qz));
    unsigned mort = (expand10((unsigned)qx) << 2) |
                    (expand10((unsigned)qy) << 1) | expand10((unsigned)qz);
    keys[p] = ((unsigned long long)mort << 14) | (unsigned)p;
  }
  __syncthreads();
  for (unsigned k = 2; k <= (unsigned)kN; k <<= 1) {
    for (unsigned j = k >> 1; j > 0; j >>= 1) {
      for (int i = t; i < kN; i += 1024) {
        int l = i ^ (int)j;
        if (l > i) {
          unsigned long long a = keys[i], c = keys[l];
          bool asc = ((i & (int)k) == 0);
          if ((a > c) == asc) { keys[i] = c; keys[l] = a; }
        }
      }
      __syncthreads();
    }
  }
  float* FX = px4 + (size_t)b * kN;
  float* FY = py4 + (size_t)b * kN;
  float* FZ = pz4 + (size_t)b * kN;
  unsigned* FO = po4 + (size_t)b * kN;
  for (int i = t; i < kN; i += 1024) {
    int o = (int)(keys[i] & 0x3FFFull);
    int c = i >> 4, j = i & 15;
    int fi = (((c << 2) | (j & 3)) << 2) | (j >> 2);   // entry (c*4+q), elem slot
    FX[fi] = P[o * 3];
    FY[fi] = P[o * 3 + 1];
    FZ[fi] = P[o * 3 + 2];
    FO[fi] = 16383u - (unsigned)o;   // tie key: max(16383-o) == min orig
  }
  // 16-pt chunk AABB: center + inflated half-extents (covers fp rounding)
  if (t < kNC16) {
    float amn = 3e38f, bmn = 3e38f, cmn = 3e38f;
    float amx = -3e38f, bmx = -3e38f, cmx = -3e38f;
    for (int kk = 0; kk < 16; kk++) {
      int o = (int)(keys[t * 16 + kk] & 0x3FFFull);
      float x = P[o * 3], y = P[o * 3 + 1], z = P[o * 3 + 2];
      amn = fminf(amn, x); amx = fmaxf(amx, x);
      bmn = fminf(bmn, y); bmx = fmaxf(bmx, y);
      cmn = fminf(cmn, z); cmx = fmaxf(cmx, z);
    }
    float* AB = aabb + (size_t)b * 6 * kNC16;
    AB[0 * kNC16 + t] = (amn + amx) * 0.5f;
    AB[1 * kNC16 + t] = (bmn + bmx) * 0.5f;
    AB[2 * kNC16 + t] = (cmn + cmx) * 0.5f;
    AB[3 * kNC16 + t] = (amx - amn) * 0.5f * 1.0001f + 2e-7f;
    AB[4 * kNC16 + t] = (bmx - bmn) * 0.5f * 1.0001f + 2e-7f;
    AB[5 * kNC16 + t] = (cmx - cmn) * 0.5f * 1.0001f + 2e-7f;
  }
}

// -------- FPS v10: 16-pt chunks, AABB prune, pack-4, 16 chunks/pass --------
// Wave w owns chunks {(l<<4)|w}; lane l prune-tests its chunk (AABB meta in
// registers, asm-pinned). Failing chunks compacted to a per-wave LDS list;
// each pass covers 16 chunks: 4-lane quad per chunk, 4 pts/lane via float4
// plane loads + v_pk_* (IEEE RNE per half, proven R5). Quad reductions =
// 2-step quad_perm DPP (value chain, then tie chain over 16383-orig keys:
// max == numpy first-max). D4 min-dist LDS is XOR-swizzled (entry ^ (cl&7))
// to break the 16-way bank aliasing the uniform w-field would cause.
// Phase 2 (u64-DPP wave max -> LDS dbuf -> barrier -> 16-key reduce ->
// broadcast coord load) unchanged from R8/R9. One barrier per iteration.
__global__ __launch_bounds__(1024) void fps_kernel(
    const float* __restrict__ xyz,
    const float4* __restrict__ px4, const float4* __restrict__ py4,
    const float4* __restrict__ pz4, const uint4* __restrict__ po4,
    const float* __restrict__ aabb, float* __restrict__ new_xyz) {
  const int b = blockIdx.x;
  const int t = threadIdx.x;
  const int lane = t & 63;
  const int w = t >> 6;
  const int grp4 = lane >> 2;       // quad id = chunk slot within a pass
  const int sub4 = lane & 3;        // lane within quad
  const int s0 = (w << 6) | lane;   // M2 slot owned by this lane
  const float* P = xyz + (size_t)b * kN * 3;
  const float4* XP = px4 + (size_t)b * (kN / 4);
  const float4* YP = py4 + (size_t)b * (kN / 4);
  const float4* ZP = pz4 + (size_t)b * (kN / 4);
  const uint4* OP = po4 + (size_t)b * (kN / 4);

  __shared__ f32x4 D4[kNC16 * 4];     // 64 KB  per-(chunk,quad-lane) min dists
  __shared__ uint2 M2[kNC16];         // 8 KB   per-chunk key {fbits, tie}
  __shared__ unsigned list_[16][64];  // 4 KB   per-wave failing-chunk list
  __shared__ unsigned whi[2][16], wlo[2][16];

  for (int i = t; i < kNC16 * 4; i += 1024) D4[i] = f32x4{1e10f, 1e10f, 1e10f, 1e10f};
  if (t < kNC16) M2[t] = uint2{__float_as_uint(1e10f), 0u};

  // AABB meta for this lane's chunk -> registers, pinned opaque (R5 trick)
  const int c0 = (lane << 4) | w;
  const float* AB = aabb + (size_t)b * 6 * kNC16;
  float ux = AB[c0], uy = AB[kNC16 + c0], uz = AB[2 * kNC16 + c0];
  float hx = AB[3 * kNC16 + c0], hy = AB[4 * kNC16 + c0], hz = AB[5 * kNC16 + c0];
  asm volatile("" : "+v"(ux), "+v"(uy), "+v"(uz), "+v"(hx), "+v"(hy), "+v"(hz));
  __syncthreads();

  float cx = P[0], cy = P[1], cz = P[2];

  for (int it = 0; it < kS; ++it) {
    if (t == 0) {
      float* o = new_xyz + ((size_t)b * kS + it) * 3;
      o[0] = cx; o[1] = cy; o[2] = cz;
    }
    // ---- AABB prune (conservative, exact-skip proven R6/R9) ----
    {
      float txd = fmaxf(fabsf(cx - ux) - hx, 0.0f);
      float tyd = fmaxf(fabsf(cy - uy) - hy, 0.0f);
      float tzd = fmaxf(fabsf(cz - uz) - hz, 0.0f);
      float lb2 = txd * txd + tyd * tyd + tzd * tzd;
      float Mv = __uint_as_float(M2[s0].x);
      bool fail = !(lb2 >= Mv * 1.00001f + 1e-5f);
      unsigned long long fmask = __ballot(fail);
      int nf = (int)__popcll(fmask);
      if (fail) {
        int pos = (int)__popcll(fmask & ((1ull << lane) - 1ull));
        list_[w][pos] = (unsigned)lane;
      }
      const f32x2 ncx = f32x2{-cx, -cx};
      const f32x2 ncy = f32x2{-cy, -cy};
      const f32x2 ncz = f32x2{-cz, -cz};
      const int npass = (nf + 15) >> 4;
      for (int i = 0; i < npass; ++i) {
        int idx = min(i * 16 + grp4, nf - 1);   // tail replication: benign
        int cl = (int)list_[w][idx];
        int pe = (((cl << 4) | w) << 2) | sub4; // plane entry (c*4 + q)
        int de = pe ^ (cl & 7);                 // swizzled D4 entry (bijective)
        float4 xq = XP[pe], yq = YP[pe], zq = ZP[pe];
        uint4 oq = OP[pe];
        f32x4 dold = D4[de];
        f32x2 xa{xq.x, xq.y}, xb{xq.z, xq.w};
        f32x2 ya{yq.x, yq.y}, yb{yq.z, yq.w};
        f32x2 za{zq.x, zq.y}, zb{zq.z, zq.w};
        f32x2 dxa, dxb, dya, dyb, dza, dzb, s1a, s1b, d2a, d2b;
        PK_ADD(dxa, xa, ncx); PK_ADD(dxb, xb, ncx);  // p+(-c) == p-c exactly
        PK_ADD(dya, ya, ncy); PK_ADD(dyb, yb, ncy);
        PK_ADD(dza, za, ncz); PK_ADD(dzb, zb, ncz);
        PK_MUL(dxa, dxa, dxa); PK_MUL(dxb, dxb, dxb);
        PK_MUL(dya, dya, dya); PK_MUL(dyb, dyb, dyb);
        PK_MUL(dza, dza, dza); PK_MUL(dzb, dzb, dzb);
        PK_ADD(s1a, dxa, dya); PK_ADD(s1b, dxb, dyb);
        PK_ADD(d2a, s1a, dza); PK_ADD(d2b, s1b, dzb);
        f32x4 dk;
        dk.x = fminf(dold.x, d2a.x);
        dk.y = fminf(dold.y, d2a.y);
        dk.z = fminf(dold.z, d2b.x);
        dk.w = fminf(dold.w, d2b.y);
        D4[de] = dk;
        unsigned f0 = __float_as_uint(dk.x), f1 = __float_as_uint(dk.y);
        unsigned f2 = __float_as_uint(dk.z), f3 = __float_as_uint(dk.w);
        unsigned mx = max4(max(max(f0, f1), max(f2, f3)));  // bit-max==fmax (>=0)
        unsigned t0 = (f0 == mx) ? oq.x : 0u;
        unsigned t1 = (f1 == mx) ? oq.y : 0u;
        unsigned t2 = (f2 == mx) ? oq.z : 0u;
        unsigned t3 = (f3 == mx) ? oq.w : 0u;
        unsigned tv = max4(max(max(t0, t1), max(t2, t3)));  // min orig among ties
        if (sub4 == 0) M2[(w << 6) | cl] = uint2{mx, tv};
      }
    }
    // ---- phase 2a: per-wave u64 key max over own 64 slots (lane63) ----
    {
      uint2 m = M2[s0];
      unsigned hi = m.x, lo = m.y;
      u64max_dpp<0xB1>(hi, lo);
      u64max_dpp<0x4E>(hi, lo);
      u64max_dpp<0x124>(hi, lo);   // row_ror:4
      u64max_dpp<0x128>(hi, lo);   // row_ror:8
      u64max_dpp<0x142>(hi, lo);   // row_bcast:15
      u64max_dpp<0x143>(hi, lo);   // row_bcast:31 -> lane 63 valid
      if (lane == 63) { whi[it & 1][w] = hi; wlo[it & 1][w] = lo; }
    }
    __syncthreads();
    // ---- phase 2b: global max over 16 wave keys; coords via L2 broadcast --
    {
      unsigned hi = whi[it & 1][lane & 15], lo = wlo[it & 1][lane & 15];
      u64max_dpp<0x121>(hi, lo);
      u64max_dpp<0x122>(hi, lo);
      u64max_dpp<0x124>(hi, lo);
      u64max_dpp<0x128>(hi, lo);   // all lanes hold global max key
      int orig = 16383 - (int)(lo & 0x3FFFu);
      cx = P[orig * 3];
      cy = P[orig * 3 + 1];
      cz = P[orig * 3 + 2];
    }
  }
}

// -------- ball query: one wave per query, first-32 ascending indices --------
__global__ __launch_bounds__(256) void ball_query_kernel(const float* __restrict__ xyz,
                                                         const float* __restrict__ new_xyz,
                                                         int* __restrict__ idx) {
  const int q = (int)((blockIdx.x * 256 + threadIdx.x) >> 6);
  const int lane = threadIdx.x & 63;
  const int b = q >> 12;
  const float* P = xyz + (size_t)b * kN * 3;
  const float qx = new_xyz[q * 3 + 0];
  const float qy = new_xyz[q * 3 + 1];
  const float qz = new_xyz[q * 3 + 2];
  int cnt = 0;
  int first = -1;
  const int base = q * kNS;
  for (int j = 0; j < kN / 64; j++) {
    const int p = (j << 6) + lane;
    float dx = P[p * 3 + 0] - qx;
    float dy = P[p * 3 + 1] - qy;
    float dz = P[p * 3 + 2] - qz;
    float d = __fadd_rn(__fadd_rn(__fmul_rn(dx, dx), __fmul_rn(dy, dy)),
                        __fmul_rn(dz, dz));
    bool inb = d < 0.25f;
    unsigned long long m = __ballot(inb);
    if (first < 0 && m != 0ull) first = (j << 6) + (__ffsll(m) - 1);
    if (inb && cnt < kNS) {
      int r = cnt + (int)__popcll(m & ((1ull << lane) - 1ull));
      if (r < kNS) idx[base + r] = p;
    }
    cnt += (int)__popcll(m);
    if (cnt >= kNS) break;
  }
  if (cnt < kNS) {
    int fill = (first >= 0) ? first : 0;
    if (lane >= cnt && lane < kNS) idx[base + lane] = fill;
  }
}

// -------- gather + MLP(67->64->64->128) + maxpool + agg(128->128) + score ----
__global__ __launch_bounds__(128) void group_mlp_kernel(
    const float* __restrict__ xyz, const float* __restrict__ new_xyz,
    const float* __restrict__ featsT, const int* __restrict__ nidx,
    const float* __restrict__ w1, const float* __restrict__ b1,
    const float* __restrict__ w2, const float* __restrict__ b2,
    const float* __restrict__ w3, const float* __restrict__ b3,
    const float* __restrict__ wa, const float* __restrict__ ba,
    const float* __restrict__ wc, const float* __restrict__ bc,
    float* __restrict__ aggT, float* __restrict__ scores) {
  __shared__ float smem[2 * 4384];
  const int wid = threadIdx.x >> 6;
  const int lane = threadIdx.x & 63;
  const int q = blockIdx.x * 2 + wid;
  const int b = q >> 12;
  float* Xs = smem + wid * 4384;   // [32][68] input; later reused as H2 [32][64]
  float* H1 = Xs + 32 * 68;        // [32][64]
  float* pool = H1 + 32 * 64;      // [128]
  int* idxs = (int*)(pool + 128);  // [32]

  if (lane < 32) idxs[lane] = nidx[q * kNS + lane];
  const float qx = new_xyz[q * 3 + 0];
  const float qy = new_xyz[q * 3 + 1];
  const float qz = new_xyz[q * 3 + 2];
  __syncthreads();

  const float* P = xyz + (size_t)b * kN * 3;
  const float* F = featsT + (size_t)b * kN * kC;
  if (lane < 32) {
    int p = idxs[lane];
    Xs[lane * 68 + 0] = P[p * 3 + 0] - qx;
    Xs[lane * 68 + 1] = P[p * 3 + 1] - qy;
    Xs[lane * 68 + 2] = P[p * 3 + 2] - qz;
  } else {
    Xs[(lane - 32) * 68 + 67] = 0.0f;   // pad column
  }
  for (int j = 0; j < 32; j++) {
    Xs[j * 68 + 3 + lane] = F[(size_t)idxs[j] * kC + lane];
  }
  __syncthreads();

  float w[68];
  // ---- layer 1: 67 -> 64, lane = out channel ----
  {
    const int o = lane;
#pragma unroll
    for (int k = 0; k < 67; k++) w[k] = w1[o * 67 + k];
    w[67] = 0.0f;
    const float bias = b1[o];
    for (int r = 0; r < 32; r++) {
      float acc = bias;
#pragma unroll
      for (int k4 = 0; k4 < 17; k4++) {
        float4 x = *(const float4*)&Xs[r * 68 + k4 * 4];
        acc += x.x * w[k4 * 4 + 0] + x.y * w[k4 * 4 + 1] +
               x.z * w[k4 * 4 + 2] + x.w * w[k4 * 4 + 3];
      }
      H1[r * 64 + o] = fmaxf(acc, 0.0f);
    }
  }
  __syncthreads();
  // ---- layer 2: 64 -> 64, write H2 into Xs region ----
  {
    const int o = lane;
#pragma unroll
    for (int k = 0; k < 64; k++) w[k] = w2[o * 64 + k];
    const float bias = b2[o];
    for (int r = 0; r < 32; r++) {
      float acc = bias;
#pragma unroll
      for (int k4 = 0; k4 < 16; k4++) {
        float4 x = *(const float4*)&H1[r * 64 + k4 * 4];
        acc += x.x * w[k4 * 4 + 0] + x.y * w[k4 * 4 + 1] +
               x.z * w[k4 * 4 + 2] + x.w * w[k4 * 4 + 3];
      }
      Xs[r * 64 + o] = fmaxf(acc, 0.0f);
    }
  }
  __syncthreads();
  // ---- layer 3: 64 -> 128 (2 out channels per lane) + maxpool over rows ----
  {
    const int c = lane;
    float wB[64];
#pragma unroll
    for (int k = 0; k < 64; k++) {
      w[k] = w3[c * 64 + k];
      wB[k] = w3[(c + 64) * 64 + k];
    }
    const float biasA = b3[c];
    const float biasB = b3[c + 64];
    float pa = 0.0f, pb = 0.0f;   // relu folded: max over relu(h) == max(0, max h)
    for (int r = 0; r < 32; r++) {
      float a = biasA, bb = biasB;
#pragma unroll
      for (int k4 = 0; k4 < 16; k4++) {
        float4 x = *(const float4*)&Xs[r * 64 + k4 * 4];
        a  += x.x * w[k4 * 4 + 0] + x.y * w[k4 * 4 + 1] +
              x.z * w[k4 * 4 + 2] + x.w * w[k4 * 4 + 3];
        bb += x.x * wB[k4 * 4 + 0] + x.y * wB[k4 * 4 + 1] +
              x.z * wB[k4 * 4 + 2] + x.w * wB[k4 * 4 + 3];
      }
      pa = fmaxf(pa, a);
      pb = fmaxf(pb, bb);
    }
    pool[c] = pa;
    pool[c + 64] = pb;
  }
  __syncthreads();
  // ---- aggregation 128->128 + relu, confidence 128->1 ----
  {
    const int c = lane;
    float accA = ba[c], accB = ba[c + 64];
#pragma unroll
    for (int k4 = 0; k4 < 32; k4++) {
      float4 pv = *(const float4*)&pool[k4 * 4];
      float4 wva = *(const float4*)&wa[c * 128 + k4 * 4];
      float4 wvb = *(const float4*)&wa[(c + 64) * 128 + k4 * 4];
      accA += pv.x * wva.x + pv.y * wva.y + pv.z * wva.z + pv.w * wva.w;
      accB += pv.x * wvb.x + pv.y * wvb.y + pv.z * wvb.z + pv.w * wvb.w;
    }
    float aggA = fmaxf(accA, 0.0f);
    float aggB = fmaxf(accB, 0.0f);
    aggT[(size_t)q * 128 + c] = aggA;
    aggT[(size_t)q * 128 + 64 + c] = aggB;
    float partial = aggA * wc[c] + aggB * wc[c + 64];
#pragma unroll
    for (int off = 32; off >= 1; off >>= 1) partial += __shfl_xor(partial, off, 64);
    if (lane == 0) scores[q] = partial + bc[0];
  }
}

extern "C" void kernel_launch(void* const* d_in, const int* in_sizes, int n_in,
                              void* d_out, int out_size, void* d_ws, size_t ws_size,
                              hipStream_t stream) {
  const float* xyz   = (const float*)d_in[0];
  const float* feats = (const float*)d_in[1];
  const float* w1 = (const float*)d_in[2];
  const float* b1 = (const float*)d_in[3];
  const float* w2 = (const float*)d_in[4];
  const float* b2 = (const float*)d_in[5];
  const float* w3 = (const float*)d_in[6];
  const float* b3 = (const float*)d_in[7];
  const float* wa = (const float*)d_in[8];
  const float* ba = (const float*)d_in[9];
  const float* wc = (const float*)d_in[10];
  const float* bc = (const float*)d_in[11];

  float* out_new_xyz = (float*)d_out;                               // B*S*3
  float* out_feat    = out_new_xyz + (size_t)kB * kS * 3;           // B*128*S
  float* out_scores  = out_feat + (size_t)kB * 128 * kS;            // B*S

  // ws layout: featsT [0,8MiB), idx [8MiB,9MiB), aggT [9MiB,13MiB).
  // FPS-prep buffers ALIAS the aggT region (consumed before group_mlp writes):
  // px4/py4/pz4/po4 4x128KB, aabb 48KB.
  char* ws = (char*)d_ws;
  float* featsT = (float*)ws;
  int*   idxbuf = (int*)(ws + (size_t)8 * 1024 * 1024);
  float* aggT   = (float*)(ws + (size_t)9 * 1024 * 1024);
  float*    px4 = (float*)(ws + (size_t)9 * 1024 * 1024);
  float*    py4 = (float*)(ws + (size_t)9 * 1024 * 1024 + 128 * 1024);
  float*    pz4 = (float*)(ws + (size_t)9 * 1024 * 1024 + 256 * 1024);
  unsigned* po4 = (unsigned*)(ws + (size_t)9 * 1024 * 1024 + 384 * 1024);
  float*   aabb = (float*)(ws + (size_t)9 * 1024 * 1024 + 512 * 1024);

  transpose_kernel<<<dim3(kN / 32, kC / 32, kB), dim3(32, 8, 1), 0, stream>>>(
      feats, featsT, kC, kN);
  fps_prep_kernel<<<dim3(kB), dim3(1024), 0, stream>>>(
      xyz, px4, py4, pz4, po4, aabb);
  fps_kernel<<<dim3(kB), dim3(1024), 0, stream>>>(
      xyz, (const float4*)px4, (const float4*)py4, (const float4*)pz4,
      (const uint4*)po4, aabb, out_new_xyz);
  ball_query_kernel<<<dim3(kB * kS / 4), dim3(256), 0, stream>>>(
      xyz, out_new_xyz, idxbuf);
  group_mlp_kernel<<<dim3(kB * kS / 2), dim3(128), 0, stream>>>(
      xyz, out_new_xyz, featsT, idxbuf,
      w1, b1, w2, b2, w3, b3, wa, ba, wc, bc, aggT, out_scores);
  transpose_kernel<<<dim3(128 / 32, kS / 32, kB), dim3(32, 8, 1), 0, stream>>>(
      aggT, out_feat, kS, 128);
}

// Round 11
// 6382.391 us; speedup vs baseline: 1.0971x; 1.0971x over previous
//
#include <hip/hip_runtime.h>
#include <cstddef>

constexpr int kB = 2;
constexpr int kN = 16384;
constexpr int kC = 64;
constexpr int kS = 4096;    // NPOINT
constexpr int kNS = 32;     // NSAMPLE
constexpr int kNC16 = 1024; // 16-point chunks per batch
constexpr int kNP = kN / 2; // point pairs per batch

typedef float f32x2 __attribute__((ext_vector_type(2)));

__device__ __forceinline__ unsigned expand10(unsigned v) {
  v &= 1023u;
  v = (v | (v << 16)) & 0x030000FFu;
  v = (v | (v <<  8)) & 0x0300F00Fu;
  v = (v | (v <<  4)) & 0x030C30C3u;
  v = (v | (v <<  2)) & 0x09249249u;
  return v;
}

template <int C>
__device__ __forceinline__ unsigned dpp_u32(unsigned x) {
  return (unsigned)__builtin_amdgcn_update_dpp((int)x, (int)x, C, 0xF, 0xF, false);
}
// max over each aligned 8-lane group (quad xor1, xor2, half-row mirror)
__device__ __forceinline__ unsigned max8(unsigned x) {
  x = max(x, dpp_u32<0xB1>(x));   // quad_perm [1,0,3,2]
  x = max(x, dpp_u32<0x4E>(x));   // quad_perm [2,3,0,1]
  x = max(x, dpp_u32<0x141>(x));  // row_half_mirror
  return x;
}
// one u64-max DPP step on an (hi,lo) pair
template <int C>
__device__ __forceinline__ void u64max_dpp(unsigned& hi, unsigned& lo) {
  unsigned h2 = dpp_u32<C>(hi), l2 = dpp_u32<C>(lo);
  bool g = (h2 > hi) || (h2 == hi && l2 > lo);
  hi = g ? h2 : hi;
  lo = g ? l2 : lo;
}

#define PK_ADD(d, a, b) asm("v_pk_add_f32 %0, %1, %2" : "=v"(d) : "v"(a), "v"(b))
#define PK_MUL(d, a, b) asm("v_pk_mul_f32 %0, %1, %2" : "=v"(d) : "v"(a), "v"(b))

// -------- transpose [b][Cdim][Ndim] -> [b][Ndim][Cdim], 32x32 tiles --------
__global__ void transpose_kernel(const float* __restrict__ in,
                                 float* __restrict__ out,
                                 int Cdim, int Ndim) {
  __shared__ float tile[32][33];
  int b = blockIdx.z;
  int n0 = blockIdx.x * 32;
  int c0 = blockIdx.y * 32;
  int tx = threadIdx.x;
  const float* inb = in + (size_t)b * Cdim * Ndim;
  float* outb = out + (size_t)b * Cdim * Ndim;
#pragma unroll
  for (int i = threadIdx.y; i < 32; i += 8)
    tile[i][tx] = inb[(size_t)(c0 + i) * Ndim + (n0 + tx)];
  __syncthreads();
#pragma unroll
  for (int i = threadIdx.y; i < 32; i += 8)
    outb[(size_t)(n0 + i) * Cdim + (c0 + tx)] = tile[tx][i];
}

// -------- FPS prep: bbox -> morton -> in-LDS bitonic sort -> pair-SoA planes
// + 16-pt chunk AABB metadata. Sort/meta quality only affects SPEED, never
// correctness (any bijection + conservative AABB is exact).
__global__ __launch_bounds__(1024) void fps_prep_kernel(
    const float* __restrict__ xyz, float* __restrict__ pxx,
    float* __restrict__ pxy, float* __restrict__ pxz,
    unsigned* __restrict__ pxo, float* __restrict__ aabb) {
  const int b = blockIdx.x;
  const int t = threadIdx.x;
  const int lane = t & 63;
  const int w = t >> 6;
  const float* P = xyz + (size_t)b * kN * 3;
  __shared__ unsigned long long keys[kN];   // 128 KB
  __shared__ float sbb[6][16];

  float mnx = 3e38f, mny = 3e38f, mnz = 3e38f;
  float mxx = -3e38f, mxy = -3e38f, mxz = -3e38f;
  for (int p = t; p < kN; p += 1024) {
    float x = P[p * 3], y = P[p * 3 + 1], z = P[p * 3 + 2];
    mnx = fminf(mnx, x); mny = fminf(mny, y); mnz = fminf(mnz, z);
    mxx = fmaxf(mxx, x); mxy = fmaxf(mxy, y); mxz = fmaxf(mxz, z);
  }
#pragma unroll
  for (int off = 32; off >= 1; off >>= 1) {
    mnx = fminf(mnx, __shfl_xor(mnx, off, 64));
    mny = fminf(mny, __shfl_xor(mny, off, 64));
    mnz = fminf(mnz, __shfl_xor(mnz, off, 64));
    mxx = fmaxf(mxx, __shfl_xor(mxx, off, 64));
    mxy = fmaxf(mxy, __shfl_xor(mxy, off, 64));
    mxz = fmaxf(mxz, __shfl_xor(mxz, off, 64));
  }
  if (lane == 0) {
    sbb[0][w] = mnx; sbb[1][w] = mny; sbb[2][w] = mnz;
    sbb[3][w] = mxx; sbb[4][w] = mxy; sbb[5][w] = mxz;
  }
  __syncthreads();
  mnx = sbb[0][lane & 15]; mny = sbb[1][lane & 15]; mnz = sbb[2][lane & 15];
  mxx = sbb[3][lane & 15]; mxy = sbb[4][lane & 15]; mxz = sbb[5][lane & 15];
#pragma unroll
  for (int off = 8; off >= 1; off >>= 1) {
    mnx = fminf(mnx, __shfl_xor(mnx, off, 64));
    mny = fminf(mny, __shfl_xor(mny, off, 64));
    mnz = fminf(mnz, __shfl_xor(mnz, off, 64));
    mxx = fmaxf(mxx, __shfl_xor(mxx, off, 64));
    mxy = fmaxf(mxy, __shfl_xor(mxy, off, 64));
    mxz = fmaxf(mxz, __shfl_xor(mxz, off, 64));
  }
  __syncthreads();
  const float sx = 1023.0f / fmaxf(mxx - mnx, 1e-20f);
  const float sy = 1023.0f / fmaxf(mxy - mny, 1e-20f);
  const float sz = 1023.0f / fmaxf(mxz - mnz, 1e-20f);
  for (int p = t; p < kN; p += 1024) {
    float x = P[p * 3], y = P[p * 3 + 1], z = P[p * 3 + 2];
    int qx = (int)((x - mnx) * sx); qx = max(0, min(1023, qx));
    int qy = (int)((y - mny) * sy); qy = max(0, min(1023, qy));
    int qz = (int)((z - mnz) * sz); qz = max(0, min(1023, qz));
    unsigned mort = (expand10((unsigned)qx) << 2) |
                    (expand10((unsigned)qy) << 1) | expand10((unsigned)qz);
    keys[p] = ((unsigned long long)mort << 14) | (unsigned)p;
  }
  __syncthreads();
  for (unsigned k = 2; k <= (unsigned)kN; k <<= 1) {
    for (unsigned j = k >> 1; j > 0; j >>= 1) {
      for (int i = t; i < kN; i += 1024) {
        int l = i ^ (int)j;
        if (l > i) {
          unsigned long long a = keys[i], c = keys[l];
          bool asc = ((i & (int)k) == 0);
          if ((a > c) == asc) { keys[i] = c; keys[l] = a; }
        }
      }
      __syncthreads();
    }
  }
  // pair-SoA planes: pair j of chunk c holds sorted points c*16+j (.x half)
  // and c*16+j+8 (.y half). Float index = c*16 + (j&7)*2 + (j>>3).
  float* FX = pxx + (size_t)b * kN;
  float* FY = pxy + (size_t)b * kN;
  float* FZ = pxz + (size_t)b * kN;
  unsigned* FO = pxo + (size_t)b * kN;
  for (int i = t; i < kN; i += 1024) {
    int o = (int)(keys[i] & 0x3FFFull);
    int c = i >> 4, j = i & 15;
    int fi = c * 16 + ((j & 7) << 1) + (j >> 3);
    FX[fi] = P[o * 3];
    FY[fi] = P[o * 3 + 1];
    FZ[fi] = P[o * 3 + 2];
    FO[fi] = 16383u - (unsigned)o;   // tie key: max(16383-o) == min orig
  }
  // 16-pt chunk AABB: center + inflated half-extents (covers fp rounding)
  if (t < kNC16) {
    float amn = 3e38f, bmn = 3e38f, cmn = 3e38f;
    float amx = -3e38f, bmx = -3e38f, cmx = -3e38f;
    for (int kk = 0; kk < 16; kk++) {
      int o = (int)(keys[t * 16 + kk] & 0x3FFFull);
      float x = P[o * 3], y = P[o * 3 + 1], z = P[o * 3 + 2];
      amn = fminf(amn, x); amx = fmaxf(amx, x);
      bmn = fminf(bmn, y); bmx = fmaxf(bmx, y);
      cmn = fminf(cmn, z); cmx = fmaxf(cmx, z);
    }
    float* AB = aabb + (size_t)b * 6 * kNC16;
    AB[0 * kNC16 + t] = (amn + amx) * 0.5f;
    AB[1 * kNC16 + t] = (bmn + bmx) * 0.5f;
    AB[2 * kNC16 + t] = (cmn + cmx) * 0.5f;
    AB[3 * kNC16 + t] = (amx - amn) * 0.5f * 1.0001f + 2e-7f;
    AB[4 * kNC16 + t] = (bmx - bmn) * 0.5f * 1.0001f + 2e-7f;
    AB[5 * kNC16 + t] = (cmx - cmn) * 0.5f * 1.0001f + 2e-7f;
  }
}

// -------- FPS v11: R9 structure + software-pipelined pass loop --------
// Identical semantics to R9 (best-known: AABB reg-pinned prune, compacted
// list, 8 chunks/pass, pack-2 pk RNE math, u64-key DPP argmax, 1 barrier).
// NEW: operands for pass i+1 (4 global loads + dpair LDS read) are issued
// BEFORE pass i's compute, hiding L2 latency that R10 exposed (R10 lesson:
// the pass chain is latency-bound at low pass counts, not issue-bound).
__global__ __launch_bounds__(1024) void fps_kernel(
    const float* __restrict__ xyz,
    const float* __restrict__ pxx, const float* __restrict__ pxy,
    const float* __restrict__ pxz, const unsigned* __restrict__ pxo,
    const float* __restrict__ aabb, float* __restrict__ new_xyz) {
  const int b = blockIdx.x;
  const int t = threadIdx.x;
  const int lane = t & 63;
  const int w = t >> 6;
  const int grp = lane >> 3;        // 8-lane group id (chunk slot in pass)
  const int sub8 = lane & 7;        // lane within group (pair index)
  const int s0 = (w << 6) | lane;   // M2 slot owned by this lane
  const float* P = xyz + (size_t)b * kN * 3;
  const f32x2* XP = (const f32x2*)(pxx + (size_t)b * kN);
  const f32x2* YP = (const f32x2*)(pxy + (size_t)b * kN);
  const f32x2* ZP = (const f32x2*)(pxz + (size_t)b * kN);
  const uint2* OP = (const uint2*)(pxo + (size_t)b * kN);

  __shared__ f32x2 dpair[kNP];        // 64 KB  min-dist pairs
  __shared__ uint2 M2[kNC16];         // 8 KB   per-chunk key {fb, tieLo}
  __shared__ unsigned list_[16][64];  // 4 KB   per-wave failing-chunk list
  __shared__ unsigned whi[2][16], wlo[2][16];

  for (int i = t; i < kNP; i += 1024) dpair[i] = f32x2{1e10f, 1e10f};
  if (t < kNC16) M2[t] = uint2{__float_as_uint(1e10f), 0u};

  // AABB meta for this lane's chunk -> registers, pinned opaque (R5 trick)
  const int c0 = (lane << 4) | w;
  const float* AB = aabb + (size_t)b * 6 * kNC16;
  float ux = AB[c0], uy = AB[kNC16 + c0], uz = AB[2 * kNC16 + c0];
  float hx = AB[3 * kNC16 + c0], hy = AB[4 * kNC16 + c0], hz = AB[5 * kNC16 + c0];
  asm volatile("" : "+v"(ux), "+v"(uy), "+v"(uz), "+v"(hx), "+v"(hy), "+v"(hz));
  __syncthreads();

  float cx = P[0], cy = P[1], cz = P[2];

  for (int it = 0; it < kS; ++it) {
    if (t == 0) {
      float* o = new_xyz + ((size_t)b * kS + it) * 3;
      o[0] = cx; o[1] = cy; o[2] = cz;
    }
    // ---- AABB prune (conservative, exact-skip proven R6/R9) ----
    {
      float txd = fmaxf(fabsf(cx - ux) - hx, 0.0f);
      float tyd = fmaxf(fabsf(cy - uy) - hy, 0.0f);
      float tzd = fmaxf(fabsf(cz - uz) - hz, 0.0f);
      float lb2 = txd * txd + tyd * tyd + tzd * tzd;
      float Mv = __uint_as_float(M2[s0].x);
      bool fail = !(lb2 >= Mv * 1.00001f + 1e-5f);
      unsigned long long fmask = __ballot(fail);
      int nf = (int)__popcll(fmask);
      if (fail) {
        int pos = (int)__popcll(fmask & ((1ull << lane) - 1ull));
        list_[w][pos] = (unsigned)lane;
      }
      const f32x2 ncx = f32x2{-cx, -cx};
      const f32x2 ncy = f32x2{-cy, -cy};
      const f32x2 ncz = f32x2{-cz, -cz};
      if (nf > 0) {
        const int npass = (nf + 7) >> 3;
        // prefetch pass 0 (wave-synchronous LDS list write above is visible)
        int cl_n = (int)list_[w][min(grp, nf - 1)];
        int pb_n = (((cl_n << 4) | w) << 3) | sub8;
        f32x2 xp_n = XP[pb_n], yp_n = YP[pb_n], zp_n = ZP[pb_n];
        uint2 op_n = OP[pb_n];
        f32x2 dold_n = dpair[pb_n];
        for (int i = 0; i < npass; ++i) {
          // current pass operands
          const int cl = cl_n;
          const int pb = pb_n;
          const f32x2 xp = xp_n, yp = yp_n, zp = zp_n;
          const uint2 op = op_n;
          const f32x2 dold = dold_n;
          // issue next pass's loads before computing (hide L2 latency)
          if (i + 1 < npass) {
            int idx = min((i + 1) * 8 + grp, nf - 1);
            cl_n = (int)list_[w][idx];
            pb_n = (((cl_n << 4) | w) << 3) | sub8;
            xp_n = XP[pb_n]; yp_n = YP[pb_n]; zp_n = ZP[pb_n];
            op_n = OP[pb_n];
            dold_n = dpair[pb_n];
          }
          f32x2 dx_, dy_, dz_, xx_, yy_, zz_, s1_, d2_;
          PK_ADD(dx_, xp, ncx);   // p + (-c) == p - c exactly; square kills sign
          PK_ADD(dy_, yp, ncy);
          PK_ADD(dz_, zp, ncz);
          PK_MUL(xx_, dx_, dx_);
          PK_MUL(yy_, dy_, dy_);
          PK_MUL(zz_, dz_, dz_);
          PK_ADD(s1_, xx_, yy_);
          PK_ADD(d2_, s1_, zz_);
          f32x2 dk;
          dk.x = fminf(dold.x, d2_.x);
          dk.y = fminf(dold.y, d2_.y);
          dpair[pb] = dk;
          unsigned fa = __float_as_uint(dk.x), fbv = __float_as_uint(dk.y);
          unsigned mx = max8(max(fa, fbv));             // bit-max == fmax (>=0)
          unsigned sa = (fa == mx) ? op.x : 0u;
          unsigned sb = (fbv == mx) ? op.y : 0u;
          unsigned m2v = max8(max(sa, sb));             // max(16383-o) == min o
          if (sub8 == 0) M2[(w << 6) | cl] = uint2{mx, m2v};
        }
      }
    }
    // ---- phase 2a: per-wave u64 key max over own 64 slots (lane63) ----
    {
      uint2 m = M2[s0];
      unsigned hi = m.x, lo = m.y;
      u64max_dpp<0xB1>(hi, lo);
      u64max_dpp<0x4E>(hi, lo);
      u64max_dpp<0x124>(hi, lo);   // row_ror:4
      u64max_dpp<0x128>(hi, lo);   // row_ror:8
      u64max_dpp<0x142>(hi, lo);   // row_bcast:15
      u64max_dpp<0x143>(hi, lo);   // row_bcast:31 -> lane 63 valid
      if (lane == 63) { whi[it & 1][w] = hi; wlo[it & 1][w] = lo; }
    }
    __syncthreads();
    // ---- phase 2b: global max over 16 wave keys; coords via L2 broadcast --
    {
      unsigned hi = whi[it & 1][lane & 15], lo = wlo[it & 1][lane & 15];
      u64max_dpp<0x121>(hi, lo);
      u64max_dpp<0x122>(hi, lo);
      u64max_dpp<0x124>(hi, lo);
      u64max_dpp<0x128>(hi, lo);   // all lanes hold global max key
      int orig = 16383 - (int)(lo & 0x3FFFu);
      cx = P[orig * 3];
      cy = P[orig * 3 + 1];
      cz = P[orig * 3 + 2];
    }
  }
}

// -------- ball query: one wave per query, first-32 ascending indices --------
__global__ __launch_bounds__(256) void ball_query_kernel(const float* __restrict__ xyz,
                                                         const float* __restrict__ new_xyz,
                                                         int* __restrict__ idx) {
  const int q = (int)((blockIdx.x * 256 + threadIdx.x) >> 6);
  const int lane = threadIdx.x & 63;
  const int b = q >> 12;
  const float* P = xyz + (size_t)b * kN * 3;
  const float qx = new_xyz[q * 3 + 0];
  const float qy = new_xyz[q * 3 + 1];
  const float qz = new_xyz[q * 3 + 2];
  int cnt = 0;
  int first = -1;
  const int base = q * kNS;
  for (int j = 0; j < kN / 64; j++) {
    const int p = (j << 6) + lane;
    float dx = P[p * 3 + 0] - qx;
    float dy = P[p * 3 + 1] - qy;
    float dz = P[p * 3 + 2] - qz;
    float d = __fadd_rn(__fadd_rn(__fmul_rn(dx, dx), __fmul_rn(dy, dy)),
                        __fmul_rn(dz, dz));
    bool inb = d < 0.25f;
    unsigned long long m = __ballot(inb);
    if (first < 0 && m != 0ull) first = (j << 6) + (__ffsll(m) - 1);
    if (inb && cnt < kNS) {
      int r = cnt + (int)__popcll(m & ((1ull << lane) - 1ull));
      if (r < kNS) idx[base + r] = p;
    }
    cnt += (int)__popcll(m);
    if (cnt >= kNS) break;
  }
  if (cnt < kNS) {
    int fill = (first >= 0) ? first : 0;
    if (lane >= cnt && lane < kNS) idx[base + lane] = fill;
  }
}

// -------- gather + MLP(67->64->64->128) + maxpool + agg(128->128) + score ----
__global__ __launch_bounds__(128) void group_mlp_kernel(
    const float* __restrict__ xyz, const float* __restrict__ new_xyz,
    const float* __restrict__ featsT, const int* __restrict__ nidx,
    const float* __restrict__ w1, const float* __restrict__ b1,
    const float* __restrict__ w2, const float* __restrict__ b2,
    const float* __restrict__ w3, const float* __restrict__ b3,
    const float* __restrict__ wa, const float* __restrict__ ba,
    const float* __restrict__ wc, const float* __restrict__ bc,
    float* __restrict__ aggT, float* __restrict__ scores) {
  __shared__ float smem[2 * 4384];
  const int wid = threadIdx.x >> 6;
  const int lane = threadIdx.x & 63;
  const int q = blockIdx.x * 2 + wid;
  const int b = q >> 12;
  float* Xs = smem + wid * 4384;   // [32][68] input; later reused as H2 [32][64]
  float* H1 = Xs + 32 * 68;        // [32][64]
  float* pool = H1 + 32 * 64;      // [128]
  int* idxs = (int*)(pool + 128);  // [32]

  if (lane < 32) idxs[lane] = nidx[q * kNS + lane];
  const float qx = new_xyz[q * 3 + 0];
  const float qy = new_xyz[q * 3 + 1];
  const float qz = new_xyz[q * 3 + 2];
  __syncthreads();

  const float* P = xyz + (size_t)b * kN * 3;
  const float* F = featsT + (size_t)b * kN * kC;
  if (lane < 32) {
    int p = idxs[lane];
    Xs[lane * 68 + 0] = P[p * 3 + 0] - qx;
    Xs[lane * 68 + 1] = P[p * 3 + 1] - qy;
    Xs[lane * 68 + 2] = P[p * 3 + 2] - qz;
  } else {
    Xs[(lane - 32) * 68 + 67] = 0.0f;   // pad column
  }
  for (int j = 0; j < 32; j++) {
    Xs[j * 68 + 3 + lane] = F[(size_t)idxs[j] * kC + lane];
  }
  __syncthreads();

  float w[68];
  // ---- layer 1: 67 -> 64, lane = out channel ----
  {
    const int o = lane;
#pragma unroll
    for (int k = 0; k < 67; k++) w[k] = w1[o * 67 + k];
    w[67] = 0.0f;
    const float bias = b1[o];
    for (int r = 0; r < 32; r++) {
      float acc = bias;
#pragma unroll
      for (int k4 = 0; k4 < 17; k4++) {
        float4 x = *(const float4*)&Xs[r * 68 + k4 * 4];
        acc += x.x * w[k4 * 4 + 0] + x.y * w[k4 * 4 + 1] +
               x.z * w[k4 * 4 + 2] + x.w * w[k4 * 4 + 3];
      }
      H1[r * 64 + o] = fmaxf(acc, 0.0f);
    }
  }
  __syncthreads();
  // ---- layer 2: 64 -> 64, write H2 into Xs region ----
  {
    const int o = lane;
#pragma unroll
    for (int k = 0; k < 64; k++) w[k] = w2[o * 64 + k];
    const float bias = b2[o];
    for (int r = 0; r < 32; r++) {
      float acc = bias;
#pragma unroll
      for (int k4 = 0; k4 < 16; k4++) {
        float4 x = *(const float4*)&H1[r * 64 + k4 * 4];
        acc += x.x * w[k4 * 4 + 0] + x.y * w[k4 * 4 + 1] +
               x.z * w[k4 * 4 + 2] + x.w * w[k4 * 4 + 3];
      }
      Xs[r * 64 + o] = fmaxf(acc, 0.0f);
    }
  }
  __syncthreads();
  // ---- layer 3: 64 -> 128 (2 out channels per lane) + maxpool over rows ----
  {
    const int c = lane;
    float wB[64];
#pragma unroll
    for (int k = 0; k < 64; k++) {
      w[k] = w3[c * 64 + k];
      wB[k] = w3[(c + 64) * 64 + k];
    }
    const float biasA = b3[c];
    const float biasB = b3[c + 64];
    float pa = 0.0f, pb = 0.0f;   // relu folded: max over relu(h) == max(0, max h)
    for (int r = 0; r < 32; r++) {
      float a = biasA, bb = biasB;
#pragma unroll
      for (int k4 = 0; k4 < 16; k4++) {
        float4 x = *(const float4*)&Xs[r * 64 + k4 * 4];
        a  += x.x * w[k4 * 4 + 0] + x.y * w[k4 * 4 + 1] +
              x.z * w[k4 * 4 + 2] + x.w * w[k4 * 4 + 3];
        bb += x.x * wB[k4 * 4 + 0] + x.y * wB[k4 * 4 + 1] +
              x.z * wB[k4 * 4 + 2] + x.w * wB[k4 * 4 + 3];
      }
      pa = fmaxf(pa, a);
      pb = fmaxf(pb, bb);
    }
    pool[c] = pa;
    pool[c + 64] = pb;
  }
  __syncthreads();
  // ---- aggregation 128->128 + relu, confidence 128->1 ----
  {
    const int c = lane;
    float accA = ba[c], accB = ba[c + 64];
#pragma unroll
    for (int k4 = 0; k4 < 32; k4++) {
      float4 pv = *(const float4*)&pool[k4 * 4];
      float4 wva = *(const float4*)&wa[c * 128 + k4 * 4];
      float4 wvb = *(const float4*)&wa[(c + 64) * 128 + k4 * 4];
      accA += pv.x * wva.x + pv.y * wva.y + pv.z * wva.z + pv.w * wva.w;
      accB += pv.x * wvb.x + pv.y * wvb.y + pv.z * wvb.z + pv.w * wvb.w;
    }
    float aggA = fmaxf(accA, 0.0f);
    float aggB = fmaxf(accB, 0.0f);
    aggT[(size_t)q * 128 + c] = aggA;
    aggT[(size_t)q * 128 + 64 + c] = aggB;
    float partial = aggA * wc[c] + aggB * wc[c + 64];
#pragma unroll
    for (int off = 32; off >= 1; off >>= 1) partial += __shfl_xor(partial, off, 64);
    if (lane == 0) scores[q] = partial + bc[0];
  }
}

extern "C" void kernel_launch(void* const* d_in, const int* in_sizes, int n_in,
                              void* d_out, int out_size, void* d_ws, size_t ws_size,
                              hipStream_t stream) {
  const float* xyz   = (const float*)d_in[0];
  const float* feats = (const float*)d_in[1];
  const float* w1 = (const float*)d_in[2];
  const float* b1 = (const float*)d_in[3];
  const float* w2 = (const float*)d_in[4];
  const float* b2 = (const float*)d_in[5];
  const float* w3 = (const float*)d_in[6];
  const float* b3 = (const float*)d_in[7];
  const float* wa = (const float*)d_in[8];
  const float* ba = (const float*)d_in[9];
  const float* wc = (const float*)d_in[10];
  const float* bc = (const float*)d_in[11];

  float* out_new_xyz = (float*)d_out;                               // B*S*3
  float* out_feat    = out_new_xyz + (size_t)kB * kS * 3;           // B*128*S
  float* out_scores  = out_feat + (size_t)kB * 128 * kS;            // B*S

  // ws layout: featsT [0,8MiB), idx [8MiB,9MiB), aggT [9MiB,13MiB).
  // FPS-prep buffers ALIAS the aggT region (consumed before group_mlp writes):
  // pxx/pxy/pxz/pxo 4x128KB, aabb 48KB.
  char* ws = (char*)d_ws;
  float* featsT = (float*)ws;
  int*   idxbuf = (int*)(ws + (size_t)8 * 1024 * 1024);
  float* aggT   = (float*)(ws + (size_t)9 * 1024 * 1024);
  float*    pxx = (float*)(ws + (size_t)9 * 1024 * 1024);
  float*    pxy = (float*)(ws + (size_t)9 * 1024 * 1024 + 128 * 1024);
  float*    pxz = (float*)(ws + (size_t)9 * 1024 * 1024 + 256 * 1024);
  unsigned* pxo = (unsigned*)(ws + (size_t)9 * 1024 * 1024 + 384 * 1024);
  float*   aabb = (float*)(ws + (size_t)9 * 1024 * 1024 + 512 * 1024);

  transpose_kernel<<<dim3(kN / 32, kC / 32, kB), dim3(32, 8, 1), 0, stream>>>(
      feats, featsT, kC, kN);
  fps_prep_kernel<<<dim3(kB), dim3(1024), 0, stream>>>(
      xyz, pxx, pxy, pxz, pxo, aabb);
  fps_kernel<<<dim3(kB), dim3(1024), 0, stream>>>(
      xyz, pxx, pxy, pxz, pxo, aabb, out_new_xyz);
  ball_query_kernel<<<dim3(kB * kS / 4), dim3(256), 0, stream>>>(
      xyz, out_new_xyz, idxbuf);
  group_mlp_kernel<<<dim3(kB * kS / 2), dim3(128), 0, stream>>>(
      xyz, out_new_xyz, featsT, idxbuf,
      w1, b1, w2, b2, w3, b3, wa, ba, wc, bc, aggT, out_scores);
  transpose_kernel<<<dim3(128 / 32, kS / 32, kB), dim3(32, 8, 1), 0, stream>>>(
      aggT, out_feat, kS, 128);
}

// Round 12
// 6138.092 us; speedup vs baseline: 1.1407x; 1.0398x over previous
//
#include <hip/hip_runtime.h>
#include <cstddef>

constexpr int kB = 2;
constexpr int kN = 16384;
constexpr int kC = 64;
constexpr int kS = 4096;    // NPOINT
constexpr int kNS = 32;     // NSAMPLE
constexpr int kNC16 = 1024; // 16-point chunks per batch
constexpr int kNP = kN / 2; // point pairs per batch

typedef float f32x2 __attribute__((ext_vector_type(2)));

__device__ __forceinline__ unsigned expand10(unsigned v) {
  v &= 1023u;
  v = (v | (v << 16)) & 0x030000FFu;
  v = (v | (v <<  8)) & 0x0300F00Fu;
  v = (v | (v <<  4)) & 0x030C30C3u;
  v = (v | (v <<  2)) & 0x09249249u;
  return v;
}

template <int C>
__device__ __forceinline__ unsigned dpp_u32(unsigned x) {
  return (unsigned)__builtin_amdgcn_update_dpp((int)x, (int)x, C, 0xF, 0xF, false);
}
// max over each aligned 8-lane group (quad xor1, xor2, half-row mirror)
__device__ __forceinline__ unsigned max8(unsigned x) {
  x = max(x, dpp_u32<0xB1>(x));   // quad_perm [1,0,3,2]
  x = max(x, dpp_u32<0x4E>(x));   // quad_perm [2,3,0,1]
  x = max(x, dpp_u32<0x141>(x));  // row_half_mirror
  return x;
}
// one u64-max DPP step on an (hi,lo) pair
template <int C>
__device__ __forceinline__ void u64max_dpp(unsigned& hi, unsigned& lo) {
  unsigned h2 = dpp_u32<C>(hi), l2 = dpp_u32<C>(lo);
  bool g = (h2 > hi) || (h2 == hi && l2 > lo);
  hi = g ? h2 : hi;
  lo = g ? l2 : lo;
}

#define PK_ADD(d, a, b) asm("v_pk_add_f32 %0, %1, %2" : "=v"(d) : "v"(a), "v"(b))
#define PK_MUL(d, a, b) asm("v_pk_mul_f32 %0, %1, %2" : "=v"(d) : "v"(a), "v"(b))

// -------- transpose [b][Cdim][Ndim] -> [b][Ndim][Cdim], 32x32 tiles --------
__global__ void transpose_kernel(const float* __restrict__ in,
                                 float* __restrict__ out,
                                 int Cdim, int Ndim) {
  __shared__ float tile[32][33];
  int b = blockIdx.z;
  int n0 = blockIdx.x * 32;
  int c0 = blockIdx.y * 32;
  int tx = threadIdx.x;
  const float* inb = in + (size_t)b * Cdim * Ndim;
  float* outb = out + (size_t)b * Cdim * Ndim;
#pragma unroll
  for (int i = threadIdx.y; i < 32; i += 8)
    tile[i][tx] = inb[(size_t)(c0 + i) * Ndim + (n0 + tx)];
  __syncthreads();
#pragma unroll
  for (int i = threadIdx.y; i < 32; i += 8)
    outb[(size_t)(n0 + i) * Cdim + (c0 + tx)] = tile[tx][i];
}

// -------- FPS prep: bbox -> morton -> in-LDS bitonic sort -> pair-SoA planes
// + 16-pt chunk AABB metadata. Sort/meta quality only affects SPEED, never
// correctness (any bijection + conservative AABB is exact).
__global__ __launch_bounds__(1024) void fps_prep_kernel(
    const float* __restrict__ xyz, float* __restrict__ pxx,
    float* __restrict__ pxy, float* __restrict__ pxz,
    unsigned* __restrict__ pxo, float* __restrict__ aabb) {
  const int b = blockIdx.x;
  const int t = threadIdx.x;
  const int lane = t & 63;
  const int w = t >> 6;
  const float* P = xyz + (size_t)b * kN * 3;
  __shared__ unsigned long long keys[kN];   // 128 KB
  __shared__ float sbb[6][16];

  float mnx = 3e38f, mny = 3e38f, mnz = 3e38f;
  float mxx = -3e38f, mxy = -3e38f, mxz = -3e38f;
  for (int p = t; p < kN; p += 1024) {
    float x = P[p * 3], y = P[p * 3 + 1], z = P[p * 3 + 2];
    mnx = fminf(mnx, x); mny = fminf(mny, y); mnz = fminf(mnz, z);
    mxx = fmaxf(mxx, x); mxy = fmaxf(mxy, y); mxz = fmaxf(mxz, z);
  }
#pragma unroll
  for (int off = 32; off >= 1; off >>= 1) {
    mnx = fminf(mnx, __shfl_xor(mnx, off, 64));
    mny = fminf(mny, __shfl_xor(mny, off, 64));
    mnz = fminf(mnz, __shfl_xor(mnz, off, 64));
    mxx = fmaxf(mxx, __shfl_xor(mxx, off, 64));
    mxy = fmaxf(mxy, __shfl_xor(mxy, off, 64));
    mxz = fmaxf(mxz, __shfl_xor(mxz, off, 64));
  }
  if (lane == 0) {
    sbb[0][w] = mnx; sbb[1][w] = mny; sbb[2][w] = mnz;
    sbb[3][w] = mxx; sbb[4][w] = mxy; sbb[5][w] = mxz;
  }
  __syncthreads();
  mnx = sbb[0][lane & 15]; mny = sbb[1][lane & 15]; mnz = sbb[2][lane & 15];
  mxx = sbb[3][lane & 15]; mxy = sbb[4][lane & 15]; mxz = sbb[5][lane & 15];
#pragma unroll
  for (int off = 8; off >= 1; off >>= 1) {
    mnx = fminf(mnx, __shfl_xor(mnx, off, 64));
    mny = fminf(mny, __shfl_xor(mny, off, 64));
    mnz = fminf(mnz, __shfl_xor(mnz, off, 64));
    mxx = fmaxf(mxx, __shfl_xor(mxx, off, 64));
    mxy = fmaxf(mxy, __shfl_xor(mxy, off, 64));
    mxz = fmaxf(mxz, __shfl_xor(mxz, off, 64));
  }
  __syncthreads();
  const float sx = 1023.0f / fmaxf(mxx - mnx, 1e-20f);
  const float sy = 1023.0f / fmaxf(mxy - mny, 1e-20f);
  const float sz = 1023.0f / fmaxf(mxz - mnz, 1e-20f);
  for (int p = t; p < kN; p += 1024) {
    float x = P[p * 3], y = P[p * 3 + 1], z = P[p * 3 + 2];
    int qx = (int)((x - mnx) * sx); qx = max(0, min(1023, qx));
    int qy = (int)((y - mny) * sy); qy = max(0, min(1023, qy));
    int qz = (int)((z - mnz) * sz); qz = max(0, min(1023, qz));
    unsigned mort = (expand10((unsigned)qx) << 2) |
                    (expand10((unsigned)qy) << 1) | expand10((unsigned)qz);
    keys[p] = ((unsigned long long)mort << 14) | (unsigned)p;
  }
  __syncthreads();
  for (unsigned k = 2; k <= (unsigned)kN; k <<= 1) {
    for (unsigned j = k >> 1; j > 0; j >>= 1) {
      for (int i = t; i < kN; i += 1024) {
        int l = i ^ (int)j;
        if (l > i) {
          unsigned long long a = keys[i], c = keys[l];
          bool asc = ((i & (int)k) == 0);
          if ((a > c) == asc) { keys[i] = c; keys[l] = a; }
        }
      }
      __syncthreads();
    }
  }
  // pair-SoA planes: pair j of chunk c holds sorted points c*16+j (.x half)
  // and c*16+j+8 (.y half). Float index = c*16 + (j&7)*2 + (j>>3).
  float* FX = pxx + (size_t)b * kN;
  float* FY = pxy + (size_t)b * kN;
  float* FZ = pxz + (size_t)b * kN;
  unsigned* FO = pxo + (size_t)b * kN;
  for (int i = t; i < kN; i += 1024) {
    int o = (int)(keys[i] & 0x3FFFull);
    int c = i >> 4, j = i & 15;
    int fi = c * 16 + ((j & 7) << 1) + (j >> 3);
    FX[fi] = P[o * 3];
    FY[fi] = P[o * 3 + 1];
    FZ[fi] = P[o * 3 + 2];
    FO[fi] = 16383u - (unsigned)o;   // tie key: max(16383-o) == min orig
  }
  // 16-pt chunk AABB: center + inflated half-extents (covers fp rounding)
  if (t < kNC16) {
    float amn = 3e38f, bmn = 3e38f, cmn = 3e38f;
    float amx = -3e38f, bmx = -3e38f, cmx = -3e38f;
    for (int kk = 0; kk < 16; kk++) {
      int o = (int)(keys[t * 16 + kk] & 0x3FFFull);
      float x = P[o * 3], y = P[o * 3 + 1], z = P[o * 3 + 2];
      amn = fminf(amn, x); amx = fmaxf(amx, x);
      bmn = fminf(bmn, y); bmx = fmaxf(bmx, y);
      cmn = fminf(cmn, z); cmx = fmaxf(cmx, z);
    }
    float* AB = aabb + (size_t)b * 6 * kNC16;
    AB[0 * kNC16 + t] = (amn + amx) * 0.5f;
    AB[1 * kNC16 + t] = (bmn + bmx) * 0.5f;
    AB[2 * kNC16 + t] = (cmn + cmx) * 0.5f;
    AB[3 * kNC16 + t] = (amx - amn) * 0.5f * 1.0001f + 2e-7f;
    AB[4 * kNC16 + t] = (bmx - bmn) * 0.5f * 1.0001f + 2e-7f;
    AB[5 * kNC16 + t] = (cmx - cmn) * 0.5f * 1.0001f + 2e-7f;
  }
}

// -------- FPS v12: R9 structure + LDS winner-coords cache ------------------
// Identical parallel work to R9 (best known). NEW: each processed chunk also
// stores its winner's coords in CW[slot] (one ds_write_b128 from the unique
// matching lane-half; orig-uniqueness guarantees exactly one writer). The
// phase-2 key's lo packs the slot: lo = (tie<<10)|slot — slot bits can never
// decide a comparison (tie encodes orig uniquely), so numpy first-max
// semantics are untouched. Phase 2b then fetches the next centroid from LDS
// (broadcast ds_read_b128) instead of a dependent L2 load — removing the
// longest item in the per-iteration serial tail. Iter 0 processes ALL chunks
// (M=1e10 fails every prune), so CW/keys are fully initialized before use.
__global__ __launch_bounds__(1024) void fps_kernel(
    const float* __restrict__ xyz,
    const float* __restrict__ pxx, const float* __restrict__ pxy,
    const float* __restrict__ pxz, const unsigned* __restrict__ pxo,
    const float* __restrict__ aabb, float* __restrict__ new_xyz) {
  const int b = blockIdx.x;
  const int t = threadIdx.x;
  const int lane = t & 63;
  const int w = t >> 6;
  const int grp = lane >> 3;        // 8-lane group id (chunk slot in pass)
  const int sub8 = lane & 7;        // lane within group (pair index)
  const int s0 = (w << 6) | lane;   // M2 slot owned by this lane
  const float* P = xyz + (size_t)b * kN * 3;
  const f32x2* XP = (const f32x2*)(pxx + (size_t)b * kN);
  const f32x2* YP = (const f32x2*)(pxy + (size_t)b * kN);
  const f32x2* ZP = (const f32x2*)(pxz + (size_t)b * kN);
  const uint2* OP = (const uint2*)(pxo + (size_t)b * kN);

  __shared__ f32x2 dpair[kNP];        // 64 KB  min-dist pairs
  __shared__ uint2 M2[kNC16];         // 8 KB   per-chunk key {fb, (tie<<10)|slot}
  __shared__ float4 CW[kNC16];        // 16 KB  per-chunk winner coords
  __shared__ unsigned list_[16][64];  // 4 KB   per-wave failing-chunk list
  __shared__ unsigned whi[2][16], wlo[2][16];

  for (int i = t; i < kNP; i += 1024) dpair[i] = f32x2{1e10f, 1e10f};
  if (t < kNC16) M2[t] = uint2{__float_as_uint(1e10f), 0u};

  // AABB meta for this lane's chunk -> registers, pinned opaque (R5 trick)
  const int c0 = (lane << 4) | w;
  const float* AB = aabb + (size_t)b * 6 * kNC16;
  float ux = AB[c0], uy = AB[kNC16 + c0], uz = AB[2 * kNC16 + c0];
  float hx = AB[3 * kNC16 + c0], hy = AB[4 * kNC16 + c0], hz = AB[5 * kNC16 + c0];
  asm volatile("" : "+v"(ux), "+v"(uy), "+v"(uz), "+v"(hx), "+v"(hy), "+v"(hz));
  __syncthreads();

  float cx = P[0], cy = P[1], cz = P[2];

  for (int it = 0; it < kS; ++it) {
    if (t == 0) {
      float* o = new_xyz + ((size_t)b * kS + it) * 3;
      o[0] = cx; o[1] = cy; o[2] = cz;
    }
    // ---- AABB prune (conservative, exact-skip proven R6/R9) ----
    {
      float txd = fmaxf(fabsf(cx - ux) - hx, 0.0f);
      float tyd = fmaxf(fabsf(cy - uy) - hy, 0.0f);
      float tzd = fmaxf(fabsf(cz - uz) - hz, 0.0f);
      float lb2 = txd * txd + tyd * tyd + tzd * tzd;
      float Mv = __uint_as_float(M2[s0].x);
      bool fail = !(lb2 >= Mv * 1.00001f + 1e-5f);
      unsigned long long fmask = __ballot(fail);
      int nf = (int)__popcll(fmask);
      if (fail) {
        int pos = (int)__popcll(fmask & ((1ull << lane) - 1ull));
        list_[w][pos] = (unsigned)lane;
      }
      const f32x2 ncx = f32x2{-cx, -cx};
      const f32x2 ncy = f32x2{-cy, -cy};
      const f32x2 ncz = f32x2{-cz, -cz};
      const int npass = (nf + 7) >> 3;
      for (int i = 0; i < npass; ++i) {
        int idx = min(i * 8 + grp, nf - 1);           // tail replication: benign
        int cl = (int)list_[w][idx];
        int pb = (((cl << 4) | w) << 3) | sub8;
        f32x2 xp = XP[pb], yp = YP[pb], zp = ZP[pb];
        uint2 op = OP[pb];
        f32x2 dold = dpair[pb];
        f32x2 dx_, dy_, dz_, xx_, yy_, zz_, s1_, d2_;
        PK_ADD(dx_, xp, ncx);   // p + (-c) == p - c exactly; square kills sign
        PK_ADD(dy_, yp, ncy);
        PK_ADD(dz_, zp, ncz);
        PK_MUL(xx_, dx_, dx_);
        PK_MUL(yy_, dy_, dy_);
        PK_MUL(zz_, dz_, dz_);
        PK_ADD(s1_, xx_, yy_);
        PK_ADD(d2_, s1_, zz_);
        f32x2 dk;
        dk.x = fminf(dold.x, d2_.x);
        dk.y = fminf(dold.y, d2_.y);
        dpair[pb] = dk;
        unsigned fa = __float_as_uint(dk.x), fbv = __float_as_uint(dk.y);
        unsigned mx = max8(max(fa, fbv));             // bit-max == fmax (>=0)
        unsigned sa = (fa == mx) ? op.x : 0u;
        unsigned sb = (fbv == mx) ? op.y : 0u;
        unsigned m2v = max8(max(sa, sb));             // max(16383-o) == min o
        const int sl = (w << 6) | cl;
        if (sub8 == 0) M2[sl] = uint2{mx, (m2v << 10) | (unsigned)sl};
        // winner-coords cache: orig-uniqueness -> exactly one half matches
        if (op.x == m2v) CW[sl] = float4{xp.x, yp.x, zp.x, 0.0f};
        if (op.y == m2v) CW[sl] = float4{xp.y, yp.y, zp.y, 0.0f};
      }
    }
    // ---- phase 2a: per-wave u64 key max over own 64 slots (lane63) ----
    {
      uint2 m = M2[s0];
      unsigned hi = m.x, lo = m.y;
      u64max_dpp<0xB1>(hi, lo);
      u64max_dpp<0x4E>(hi, lo);
      u64max_dpp<0x124>(hi, lo);   // row_ror:4
      u64max_dpp<0x128>(hi, lo);   // row_ror:8
      u64max_dpp<0x142>(hi, lo);   // row_bcast:15
      u64max_dpp<0x143>(hi, lo);   // row_bcast:31 -> lane 63 valid
      if (lane == 63) { whi[it & 1][w] = hi; wlo[it & 1][w] = lo; }
    }
    __syncthreads();
    // ---- phase 2b: global max over 16 wave keys; coords via LDS broadcast --
    {
      unsigned hi = whi[it & 1][lane & 15], lo = wlo[it & 1][lane & 15];
      u64max_dpp<0x121>(hi, lo);
      u64max_dpp<0x122>(hi, lo);
      u64max_dpp<0x124>(hi, lo);
      u64max_dpp<0x128>(hi, lo);   // all lanes hold global max key
      float4 cw = CW[lo & 1023u];  // same addr across lanes -> LDS broadcast
      cx = cw.x; cy = cw.y; cz = cw.z;
    }
  }
}

// -------- ball query: one wave per query, first-32 ascending indices --------
__global__ __launch_bounds__(256) void ball_query_kernel(const float* __restrict__ xyz,
                                                         const float* __restrict__ new_xyz,
                                                         int* __restrict__ idx) {
  const int q = (int)((blockIdx.x * 256 + threadIdx.x) >> 6);
  const int lane = threadIdx.x & 63;
  const int b = q >> 12;
  const float* P = xyz + (size_t)b * kN * 3;
  const float qx = new_xyz[q * 3 + 0];
  const float qy = new_xyz[q * 3 + 1];
  const float qz = new_xyz[q * 3 + 2];
  int cnt = 0;
  int first = -1;
  const int base = q * kNS;
  for (int j = 0; j < kN / 64; j++) {
    const int p = (j << 6) + lane;
    float dx = P[p * 3 + 0] - qx;
    float dy = P[p * 3 + 1] - qy;
    float dz = P[p * 3 + 2] - qz;
    float d = __fadd_rn(__fadd_rn(__fmul_rn(dx, dx), __fmul_rn(dy, dy)),
                        __fmul_rn(dz, dz));
    bool inb = d < 0.25f;
    unsigned long long m = __ballot(inb);
    if (first < 0 && m != 0ull) first = (j << 6) + (__ffsll(m) - 1);
    if (inb && cnt < kNS) {
      int r = cnt + (int)__popcll(m & ((1ull << lane) - 1ull));
      if (r < kNS) idx[base + r] = p;
    }
    cnt += (int)__popcll(m);
    if (cnt >= kNS) break;
  }
  if (cnt < kNS) {
    int fill = (first >= 0) ? first : 0;
    if (lane >= cnt && lane < kNS) idx[base + lane] = fill;
  }
}

// -------- gather + MLP(67->64->64->128) + maxpool + agg(128->128) + score ----
__global__ __launch_bounds__(128) void group_mlp_kernel(
    const float* __restrict__ xyz, const float* __restrict__ new_xyz,
    const float* __restrict__ featsT, const int* __restrict__ nidx,
    const float* __restrict__ w1, const float* __restrict__ b1,
    const float* __restrict__ w2, const float* __restrict__ b2,
    const float* __restrict__ w3, const float* __restrict__ b3,
    const float* __restrict__ wa, const float* __restrict__ ba,
    const float* __restrict__ wc, const float* __restrict__ bc,
    float* __restrict__ aggT, float* __restrict__ scores) {
  __shared__ float smem[2 * 4384];
  const int wid = threadIdx.x >> 6;
  const int lane = threadIdx.x & 63;
  const int q = blockIdx.x * 2 + wid;
  const int b = q >> 12;
  float* Xs = smem + wid * 4384;   // [32][68] input; later reused as H2 [32][64]
  float* H1 = Xs + 32 * 68;        // [32][64]
  float* pool = H1 + 32 * 64;      // [128]
  int* idxs = (int*)(pool + 128);  // [32]

  if (lane < 32) idxs[lane] = nidx[q * kNS + lane];
  const float qx = new_xyz[q * 3 + 0];
  const float qy = new_xyz[q * 3 + 1];
  const float qz = new_xyz[q * 3 + 2];
  __syncthreads();

  const float* P = xyz + (size_t)b * kN * 3;
  const float* F = featsT + (size_t)b * kN * kC;
  if (lane < 32) {
    int p = idxs[lane];
    Xs[lane * 68 + 0] = P[p * 3 + 0] - qx;
    Xs[lane * 68 + 1] = P[p * 3 + 1] - qy;
    Xs[lane * 68 + 2] = P[p * 3 + 2] - qz;
  } else {
    Xs[(lane - 32) * 68 + 67] = 0.0f;   // pad column
  }
  for (int j = 0; j < 32; j++) {
    Xs[j * 68 + 3 + lane] = F[(size_t)idxs[j] * kC + lane];
  }
  __syncthreads();

  float w[68];
  // ---- layer 1: 67 -> 64, lane = out channel ----
  {
    const int o = lane;
#pragma unroll
    for (int k = 0; k < 67; k++) w[k] = w1[o * 67 + k];
    w[67] = 0.0f;
    const float bias = b1[o];
    for (int r = 0; r < 32; r++) {
      float acc = bias;
#pragma unroll
      for (int k4 = 0; k4 < 17; k4++) {
        float4 x = *(const float4*)&Xs[r * 68 + k4 * 4];
        acc += x.x * w[k4 * 4 + 0] + x.y * w[k4 * 4 + 1] +
               x.z * w[k4 * 4 + 2] + x.w * w[k4 * 4 + 3];
      }
      H1[r * 64 + o] = fmaxf(acc, 0.0f);
    }
  }
  __syncthreads();
  // ---- layer 2: 64 -> 64, write H2 into Xs region ----
  {
    const int o = lane;
#pragma unroll
    for (int k = 0; k < 64; k++) w[k] = w2[o * 64 + k];
    const float bias = b2[o];
    for (int r = 0; r < 32; r++) {
      float acc = bias;
#pragma unroll
      for (int k4 = 0; k4 < 16; k4++) {
        float4 x = *(const float4*)&H1[r * 64 + k4 * 4];
        acc += x.x * w[k4 * 4 + 0] + x.y * w[k4 * 4 + 1] +
               x.z * w[k4 * 4 + 2] + x.w * w[k4 * 4 + 3];
      }
      Xs[r * 64 + o] = fmaxf(acc, 0.0f);
    }
  }
  __syncthreads();
  // ---- layer 3: 64 -> 128 (2 out channels per lane) + maxpool over rows ----
  {
    const int c = lane;
    float wB[64];
#pragma unroll
    for (int k = 0; k < 64; k++) {
      w[k] = w3[c * 64 + k];
      wB[k] = w3[(c + 64) * 64 + k];
    }
    const float biasA = b3[c];
    const float biasB = b3[c + 64];
    float pa = 0.0f, pb = 0.0f;   // relu folded: max over relu(h) == max(0, max h)
    for (int r = 0; r < 32; r++) {
      float a = biasA, bb = biasB;
#pragma unroll
      for (int k4 = 0; k4 < 16; k4++) {
        float4 x = *(const float4*)&Xs[r * 64 + k4 * 4];
        a  += x.x * w[k4 * 4 + 0] + x.y * w[k4 * 4 + 1] +
              x.z * w[k4 * 4 + 2] + x.w * w[k4 * 4 + 3];
        bb += x.x * wB[k4 * 4 + 0] + x.y * wB[k4 * 4 + 1] +
              x.z * wB[k4 * 4 + 2] + x.w * wB[k4 * 4 + 3];
      }
      pa = fmaxf(pa, a);
      pb = fmaxf(pb, bb);
    }
    pool[c] = pa;
    pool[c + 64] = pb;
  }
  __syncthreads();
  // ---- aggregation 128->128 + relu, confidence 128->1 ----
  {
    const int c = lane;
    float accA = ba[c], accB = ba[c + 64];
#pragma unroll
    for (int k4 = 0; k4 < 32; k4++) {
      float4 pv = *(const float4*)&pool[k4 * 4];
      float4 wva = *(const float4*)&wa[c * 128 + k4 * 4];
      float4 wvb = *(const float4*)&wa[(c + 64) * 128 + k4 * 4];
      accA += pv.x * wva.x + pv.y * wva.y + pv.z * wva.z + pv.w * wva.w;
      accB += pv.x * wvb.x + pv.y * wvb.y + pv.z * wvb.z + pv.w * wvb.w;
    }
    float aggA = fmaxf(accA, 0.0f);
    float aggB = fmaxf(accB, 0.0f);
    aggT[(size_t)q * 128 + c] = aggA;
    aggT[(size_t)q * 128 + 64 + c] = aggB;
    float partial = aggA * wc[c] + aggB * wc[c + 64];
#pragma unroll
    for (int off = 32; off >= 1; off >>= 1) partial += __shfl_xor(partial, off, 64);
    if (lane == 0) scores[q] = partial + bc[0];
  }
}

extern "C" void kernel_launch(void* const* d_in, const int* in_sizes, int n_in,
                              void* d_out, int out_size, void* d_ws, size_t ws_size,
                              hipStream_t stream) {
  const float* xyz   = (const float*)d_in[0];
  const float* feats = (const float*)d_in[1];
  const float* w1 = (const float*)d_in[2];
  const float* b1 = (const float*)d_in[3];
  const float* w2 = (const float*)d_in[4];
  const float* b2 = (const float*)d_in[5];
  const float* w3 = (const float*)d_in[6];
  const float* b3 = (const float*)d_in[7];
  const float* wa = (const float*)d_in[8];
  const float* ba = (const float*)d_in[9];
  const float* wc = (const float*)d_in[10];
  const float* bc = (const float*)d_in[11];

  float* out_new_xyz = (float*)d_out;                               // B*S*3
  float* out_feat    = out_new_xyz + (size_t)kB * kS * 3;           // B*128*S
  float* out_scores  = out_feat + (size_t)kB * 128 * kS;            // B*S

  // ws layout: featsT [0,8MiB), idx [8MiB,9MiB), aggT [9MiB,13MiB).
  // FPS-prep buffers ALIAS the aggT region (consumed before group_mlp writes):
  // pxx/pxy/pxz/pxo 4x128KB, aabb 48KB.
  char* ws = (char*)d_ws;
  float* featsT = (float*)ws;
  int*   idxbuf = (int*)(ws + (size_t)8 * 1024 * 1024);
  float* aggT   = (float*)(ws + (size_t)9 * 1024 * 1024);
  float*    pxx = (float*)(ws + (size_t)9 * 1024 * 1024);
  float*    pxy = (float*)(ws + (size_t)9 * 1024 * 1024 + 128 * 1024);
  float*    pxz = (float*)(ws + (size_t)9 * 1024 * 1024 + 256 * 1024);
  unsigned* pxo = (unsigned*)(ws + (size_t)9 * 1024 * 1024 + 384 * 1024);
  float*   aabb = (float*)(ws + (size_t)9 * 1024 * 1024 + 512 * 1024);

  transpose_kernel<<<dim3(kN / 32, kC / 32, kB), dim3(32, 8, 1), 0, stream>>>(
      feats, featsT, kC, kN);
  fps_prep_kernel<<<dim3(kB), dim3(1024), 0, stream>>>(
      xyz, pxx, pxy, pxz, pxo, aabb);
  fps_kernel<<<dim3(kB), dim3(1024), 0, stream>>>(
      xyz, pxx, pxy, pxz, pxo, aabb, out_new_xyz);
  ball_query_kernel<<<dim3(kB * kS / 4), dim3(256), 0, stream>>>(
      xyz, out_new_xyz, idxbuf);
  group_mlp_kernel<<<dim3(kB * kS / 2), dim3(128), 0, stream>>>(
      xyz, out_new_xyz, featsT, idxbuf,
      w1, b1, w2, b2, w3, b3, wa, ba, wc, bc, aggT, out_scores);
  transpose_kernel<<<dim3(128 / 32, kS / 32, kB), dim3(32, 8, 1), 0, stream>>>(
      aggT, out_feat, kS, 128);
}

// Round 13
// 6137.186 us; speedup vs baseline: 1.1409x; 1.0001x over previous
//
#include <hip/hip_runtime.h>
#include <cstddef>

constexpr int kB = 2;
constexpr int kN = 16384;
constexpr int kC = 64;
constexpr int kS = 4096;    // NPOINT
constexpr int kNS = 32;     // NSAMPLE
constexpr int kNC16 = 1024; // 16-point chunks per batch
constexpr int kNP = kN / 2; // point pairs per batch

typedef float f32x2 __attribute__((ext_vector_type(2)));

__device__ __forceinline__ unsigned expand10(unsigned v) {
  v &= 1023u;
  v = (v | (v << 16)) & 0x030000FFu;
  v = (v | (v <<  8)) & 0x0300F00Fu;
  v = (v | (v <<  4)) & 0x030C30C3u;
  v = (v | (v <<  2)) & 0x09249249u;
  return v;
}

template <int C>
__device__ __forceinline__ unsigned dpp_u32(unsigned x) {
  return (unsigned)__builtin_amdgcn_update_dpp((int)x, (int)x, C, 0xF, 0xF, false);
}
// max over each aligned 8-lane group (quad xor1, xor2, half-row mirror)
__device__ __forceinline__ unsigned max8(unsigned x) {
  x = max(x, dpp_u32<0xB1>(x));   // quad_perm [1,0,3,2]
  x = max(x, dpp_u32<0x4E>(x));   // quad_perm [2,3,0,1]
  x = max(x, dpp_u32<0x141>(x));  // row_half_mirror
  return x;
}
// one u64-max DPP step on an (hi,lo) pair
template <int C>
__device__ __forceinline__ void u64max_dpp(unsigned& hi, unsigned& lo) {
  unsigned h2 = dpp_u32<C>(hi), l2 = dpp_u32<C>(lo);
  bool g = (h2 > hi) || (h2 == hi && l2 > lo);
  hi = g ? h2 : hi;
  lo = g ? l2 : lo;
}

#define PK_ADD(d, a, b) asm("v_pk_add_f32 %0, %1, %2" : "=v"(d) : "v"(a), "v"(b))
#define PK_MUL(d, a, b) asm("v_pk_mul_f32 %0, %1, %2" : "=v"(d) : "v"(a), "v"(b))

// -------- transpose [b][Cdim][Ndim] -> [b][Ndim][Cdim], 32x32 tiles --------
__global__ void transpose_kernel(const float* __restrict__ in,
                                 float* __restrict__ out,
                                 int Cdim, int Ndim) {
  __shared__ float tile[32][33];
  int b = blockIdx.z;
  int n0 = blockIdx.x * 32;
  int c0 = blockIdx.y * 32;
  int tx = threadIdx.x;
  const float* inb = in + (size_t)b * Cdim * Ndim;
  float* outb = out + (size_t)b * Cdim * Ndim;
#pragma unroll
  for (int i = threadIdx.y; i < 32; i += 8)
    tile[i][tx] = inb[(size_t)(c0 + i) * Ndim + (n0 + tx)];
  __syncthreads();
#pragma unroll
  for (int i = threadIdx.y; i < 32; i += 8)
    outb[(size_t)(n0 + i) * Cdim + (c0 + tx)] = tile[tx][i];
}

// -------- FPS prep: bbox -> morton -> in-LDS bitonic sort -> pair-SoA planes
// + 16-pt chunk AABB metadata. Sort/meta quality only affects SPEED, never
// correctness (any bijection + conservative AABB is exact).
__global__ __launch_bounds__(1024) void fps_prep_kernel(
    const float* __restrict__ xyz, float* __restrict__ pxx,
    float* __restrict__ pxy, float* __restrict__ pxz,
    unsigned* __restrict__ pxo, float* __restrict__ aabb) {
  const int b = blockIdx.x;
  const int t = threadIdx.x;
  const int lane = t & 63;
  const int w = t >> 6;
  const float* P = xyz + (size_t)b * kN * 3;
  __shared__ unsigned long long keys[kN];   // 128 KB
  __shared__ float sbb[6][16];

  float mnx = 3e38f, mny = 3e38f, mnz = 3e38f;
  float mxx = -3e38f, mxy = -3e38f, mxz = -3e38f;
  for (int p = t; p < kN; p += 1024) {
    float x = P[p * 3], y = P[p * 3 + 1], z = P[p * 3 + 2];
    mnx = fminf(mnx, x); mny = fminf(mny, y); mnz = fminf(mnz, z);
    mxx = fmaxf(mxx, x); mxy = fmaxf(mxy, y); mxz = fmaxf(mxz, z);
  }
#pragma unroll
  for (int off = 32; off >= 1; off >>= 1) {
    mnx = fminf(mnx, __shfl_xor(mnx, off, 64));
    mny = fminf(mny, __shfl_xor(mny, off, 64));
    mnz = fminf(mnz, __shfl_xor(mnz, off, 64));
    mxx = fmaxf(mxx, __shfl_xor(mxx, off, 64));
    mxy = fmaxf(mxy, __shfl_xor(mxy, off, 64));
    mxz = fmaxf(mxz, __shfl_xor(mxz, off, 64));
  }
  if (lane == 0) {
    sbb[0][w] = mnx; sbb[1][w] = mny; sbb[2][w] = mnz;
    sbb[3][w] = mxx; sbb[4][w] = mxy; sbb[5][w] = mxz;
  }
  __syncthreads();
  mnx = sbb[0][lane & 15]; mny = sbb[1][lane & 15]; mnz = sbb[2][lane & 15];
  mxx = sbb[3][lane & 15]; mxy = sbb[4][lane & 15]; mxz = sbb[5][lane & 15];
#pragma unroll
  for (int off = 8; off >= 1; off >>= 1) {
    mnx = fminf(mnx, __shfl_xor(mnx, off, 64));
    mny = fminf(mny, __shfl_xor(mny, off, 64));
    mnz = fminf(mnz, __shfl_xor(mnz, off, 64));
    mxx = fmaxf(mxx, __shfl_xor(mxx, off, 64));
    mxy = fmaxf(mxy, __shfl_xor(mxy, off, 64));
    mxz = fmaxf(mxz, __shfl_xor(mxz, off, 64));
  }
  __syncthreads();
  const float sx = 1023.0f / fmaxf(mxx - mnx, 1e-20f);
  const float sy = 1023.0f / fmaxf(mxy - mny, 1e-20f);
  const float sz = 1023.0f / fmaxf(mxz - mnz, 1e-20f);
  for (int p = t; p < kN; p += 1024) {
    float x = P[p * 3], y = P[p * 3 + 1], z = P[p * 3 + 2];
    int qx = (int)((x - mnx) * sx); qx = max(0, min(1023, qx));
    int qy = (int)((y - mny) * sy); qy = max(0, min(1023, qy));
    int qz = (int)((z - mnz) * sz); qz = max(0, min(1023, qz));
    unsigned mort = (expand10((unsigned)qx) << 2) |
                    (expand10((unsigned)qy) << 1) | expand10((unsigned)qz);
    keys[p] = ((unsigned long long)mort << 14) | (unsigned)p;
  }
  __syncthreads();
  for (unsigned k = 2; k <= (unsigned)kN; k <<= 1) {
    for (unsigned j = k >> 1; j > 0; j >>= 1) {
      for (int i = t; i < kN; i += 1024) {
        int l = i ^ (int)j;
        if (l > i) {
          unsigned long long a = keys[i], c = keys[l];
          bool asc = ((i & (int)k) == 0);
          if ((a > c) == asc) { keys[i] = c; keys[l] = a; }
        }
      }
      __syncthreads();
    }
  }
  // pair-SoA planes: pair j of chunk c holds sorted points c*16+j (.x half)
  // and c*16+j+8 (.y half). Float index = c*16 + (j&7)*2 + (j>>3).
  float* FX = pxx + (size_t)b * kN;
  float* FY = pxy + (size_t)b * kN;
  float* FZ = pxz + (size_t)b * kN;
  unsigned* FO = pxo + (size_t)b * kN;
  for (int i = t; i < kN; i += 1024) {
    int o = (int)(keys[i] & 0x3FFFull);
    int c = i >> 4, j = i & 15;
    int fi = c * 16 + ((j & 7) << 1) + (j >> 3);
    FX[fi] = P[o * 3];
    FY[fi] = P[o * 3 + 1];
    FZ[fi] = P[o * 3 + 2];
    FO[fi] = 16383u - (unsigned)o;   // tie key: max(16383-o) == min orig
  }
  // 16-pt chunk AABB: center + inflated half-extents (covers fp rounding)
  if (t < kNC16) {
    float amn = 3e38f, bmn = 3e38f, cmn = 3e38f;
    float amx = -3e38f, bmx = -3e38f, cmx = -3e38f;
    for (int kk = 0; kk < 16; kk++) {
      int o = (int)(keys[t * 16 + kk] & 0x3FFFull);
      float x = P[o * 3], y = P[o * 3 + 1], z = P[o * 3 + 2];
      amn = fminf(amn, x); amx = fmaxf(amx, x);
      bmn = fminf(bmn, y); bmx = fmaxf(bmx, y);
      cmn = fminf(cmn, z); cmx = fmaxf(cmx, z);
    }
    float* AB = aabb + (size_t)b * 6 * kNC16;
    AB[0 * kNC16 + t] = (amn + amx) * 0.5f;
    AB[1 * kNC16 + t] = (bmn + bmx) * 0.5f;
    AB[2 * kNC16 + t] = (cmn + cmx) * 0.5f;
    AB[3 * kNC16 + t] = (amx - amn) * 0.5f * 1.0001f + 2e-7f;
    AB[4 * kNC16 + t] = (bmx - bmn) * 0.5f * 1.0001f + 2e-7f;
    AB[5 * kNC16 + t] = (cmx - cmn) * 0.5f * 1.0001f + 2e-7f;
  }
}

// -------- FPS v12: R9 structure + LDS winner-coords cache ------------------
// Identical parallel work to R9 (best known). NEW: each processed chunk also
// stores its winner's coords in CW[slot] (one ds_write_b128 from the unique
// matching lane-half; orig-uniqueness guarantees exactly one writer). The
// phase-2 key's lo packs the slot: lo = (tie<<10)|slot — slot bits can never
// decide a comparison (tie encodes orig uniquely), so numpy first-max
// semantics are untouched. Phase 2b then fetches the next centroid from LDS
// (broadcast ds_read_b128) instead of a dependent L2 load — removing the
// longest item in the per-iteration serial tail. Iter 0 processes ALL chunks
// (M=1e10 fails every prune), so CW/keys are fully initialized before use.
__global__ __launch_bounds__(1024) void fps_kernel(
    const float* __restrict__ xyz,
    const float* __restrict__ pxx, const float* __restrict__ pxy,
    const float* __restrict__ pxz, const unsigned* __restrict__ pxo,
    const float* __restrict__ aabb, float* __restrict__ new_xyz) {
  const int b = blockIdx.x;
  const int t = threadIdx.x;
  const int lane = t & 63;
  const int w = t >> 6;
  const int grp = lane >> 3;        // 8-lane group id (chunk slot in pass)
  const int sub8 = lane & 7;        // lane within group (pair index)
  const int s0 = (w << 6) | lane;   // M2 slot owned by this lane
  const float* P = xyz + (size_t)b * kN * 3;
  const f32x2* XP = (const f32x2*)(pxx + (size_t)b * kN);
  const f32x2* YP = (const f32x2*)(pxy + (size_t)b * kN);
  const f32x2* ZP = (const f32x2*)(pxz + (size_t)b * kN);
  const uint2* OP = (const uint2*)(pxo + (size_t)b * kN);

  __shared__ f32x2 dpair[kNP];        // 64 KB  min-dist pairs
  __shared__ uint2 M2[kNC16];         // 8 KB   per-chunk key {fb, (tie<<10)|slot}
  __shared__ float4 CW[kNC16];        // 16 KB  per-chunk winner coords
  __shared__ unsigned list_[16][64];  // 4 KB   per-wave failing-chunk list
  __shared__ unsigned whi[2][16], wlo[2][16];

  for (int i = t; i < kNP; i += 1024) dpair[i] = f32x2{1e10f, 1e10f};
  if (t < kNC16) M2[t] = uint2{__float_as_uint(1e10f), 0u};

  // AABB meta for this lane's chunk -> registers, pinned opaque (R5 trick)
  const int c0 = (lane << 4) | w;
  const float* AB = aabb + (size_t)b * 6 * kNC16;
  float ux = AB[c0], uy = AB[kNC16 + c0], uz = AB[2 * kNC16 + c0];
  float hx = AB[3 * kNC16 + c0], hy = AB[4 * kNC16 + c0], hz = AB[5 * kNC16 + c0];
  asm volatile("" : "+v"(ux), "+v"(uy), "+v"(uz), "+v"(hx), "+v"(hy), "+v"(hz));
  __syncthreads();

  float cx = P[0], cy = P[1], cz = P[2];

  for (int it = 0; it < kS; ++it) {
    if (t == 0) {
      float* o = new_xyz + ((size_t)b * kS + it) * 3;
      o[0] = cx; o[1] = cy; o[2] = cz;
    }
    // ---- AABB prune (conservative, exact-skip proven R6/R9) ----
    {
      float txd = fmaxf(fabsf(cx - ux) - hx, 0.0f);
      float tyd = fmaxf(fabsf(cy - uy) - hy, 0.0f);
      float tzd = fmaxf(fabsf(cz - uz) - hz, 0.0f);
      float lb2 = txd * txd + tyd * tyd + tzd * tzd;
      float Mv = __uint_as_float(M2[s0].x);
      bool fail = !(lb2 >= Mv * 1.00001f + 1e-5f);
      unsigned long long fmask = __ballot(fail);
      int nf = (int)__popcll(fmask);
      if (fail) {
        int pos = (int)__popcll(fmask & ((1ull << lane) - 1ull));
        list_[w][pos] = (unsigned)lane;
      }
      const f32x2 ncx = f32x2{-cx, -cx};
      const f32x2 ncy = f32x2{-cy, -cy};
      const f32x2 ncz = f32x2{-cz, -cz};
      const int npass = (nf + 7) >> 3;
      for (int i = 0; i < npass; ++i) {
        int idx = min(i * 8 + grp, nf - 1);           // tail replication: benign
        int cl = (int)list_[w][idx];
        int pb = (((cl << 4) | w) << 3) | sub8;
        f32x2 xp = XP[pb], yp = YP[pb], zp = ZP[pb];
        uint2 op = OP[pb];
        f32x2 dold = dpair[pb];
        f32x2 dx_, dy_, dz_, xx_, yy_, zz_, s1_, d2_;
        PK_ADD(dx_, xp, ncx);   // p + (-c) == p - c exactly; square kills sign
        PK_ADD(dy_, yp, ncy);
        PK_ADD(dz_, zp, ncz);
        PK_MUL(xx_, dx_, dx_);
        PK_MUL(yy_, dy_, dy_);
        PK_MUL(zz_, dz_, dz_);
        PK_ADD(s1_, xx_, yy_);
        PK_ADD(d2_, s1_, zz_);
        f32x2 dk;
        dk.x = fminf(dold.x, d2_.x);
        dk.y = fminf(dold.y, d2_.y);
        dpair[pb] = dk;
        unsigned fa = __float_as_uint(dk.x), fbv = __float_as_uint(dk.y);
        unsigned mx = max8(max(fa, fbv));             // bit-max == fmax (>=0)
        unsigned sa = (fa == mx) ? op.x : 0u;
        unsigned sb = (fbv == mx) ? op.y : 0u;
        unsigned m2v = max8(max(sa, sb));             // max(16383-o) == min o
        const int sl = (w << 6) | cl;
        if (sub8 == 0) M2[sl] = uint2{mx, (m2v << 10) | (unsigned)sl};
        // winner-coords cache: orig-uniqueness -> exactly one half matches
        if (op.x == m2v) CW[sl] = float4{xp.x, yp.x, zp.x, 0.0f};
        if (op.y == m2v) CW[sl] = float4{xp.y, yp.y, zp.y, 0.0f};
      }
    }
    // ---- phase 2a: per-wave u64 key max over own 64 slots (lane63) ----
    {
      uint2 m = M2[s0];
      unsigned hi = m.x, lo = m.y;
      u64max_dpp<0xB1>(hi, lo);
      u64max_dpp<0x4E>(hi, lo);
      u64max_dpp<0x124>(hi, lo);   // row_ror:4
      u64max_dpp<0x128>(hi, lo);   // row_ror:8
      u64max_dpp<0x142>(hi, lo);   // row_bcast:15
      u64max_dpp<0x143>(hi, lo);   // row_bcast:31 -> lane 63 valid
      if (lane == 63) { whi[it & 1][w] = hi; wlo[it & 1][w] = lo; }
    }
    __syncthreads();
    // ---- phase 2b: global max over 16 wave keys; coords via LDS broadcast --
    {
      unsigned hi = whi[it & 1][lane & 15], lo = wlo[it & 1][lane & 15];
      u64max_dpp<0x121>(hi, lo);
      u64max_dpp<0x122>(hi, lo);
      u64max_dpp<0x124>(hi, lo);
      u64max_dpp<0x128>(hi, lo);   // all lanes hold global max key
      float4 cw = CW[lo & 1023u];  // same addr across lanes -> LDS broadcast
      cx = cw.x; cy = cw.y; cz = cw.z;
    }
  }
}

// -------- ball query: one wave per query, first-32 ascending indices --------
__global__ __launch_bounds__(256) void ball_query_kernel(const float* __restrict__ xyz,
                                                         const float* __restrict__ new_xyz,
                                                         int* __restrict__ idx) {
  const int q = (int)((blockIdx.x * 256 + threadIdx.x) >> 6);
  const int lane = threadIdx.x & 63;
  const int b = q >> 12;
  const float* P = xyz + (size_t)b * kN * 3;
  const float qx = new_xyz[q * 3 + 0];
  const float qy = new_xyz[q * 3 + 1];
  const float qz = new_xyz[q * 3 + 2];
  int cnt = 0;
  int first = -1;
  const int base = q * kNS;
  for (int j = 0; j < kN / 64; j++) {
    const int p = (j << 6) + lane;
    float dx = P[p * 3 + 0] - qx;
    float dy = P[p * 3 + 1] - qy;
    float dz = P[p * 3 + 2] - qz;
    float d = __fadd_rn(__fadd_rn(__fmul_rn(dx, dx), __fmul_rn(dy, dy)),
                        __fmul_rn(dz, dz));
    bool inb = d < 0.25f;
    unsigned long long m = __ballot(inb);
    if (first < 0 && m != 0ull) first = (j << 6) + (__ffsll(m) - 1);
    if (inb && cnt < kNS) {
      int r = cnt + (int)__popcll(m & ((1ull << lane) - 1ull));
      if (r < kNS) idx[base + r] = p;
    }
    cnt += (int)__popcll(m);
    if (cnt >= kNS) break;
  }
  if (cnt < kNS) {
    int fill = (first >= 0) ? first : 0;
    if (lane >= cnt && lane < kNS) idx[base + lane] = fill;
  }
}

// -------- gather + MLP(67->64->64->128) + maxpool + agg(128->128) + score ----
__global__ __launch_bounds__(128) void group_mlp_kernel(
    const float* __restrict__ xyz, const float* __restrict__ new_xyz,
    const float* __restrict__ featsT, const int* __restrict__ nidx,
    const float* __restrict__ w1, const float* __restrict__ b1,
    const float* __restrict__ w2, const float* __restrict__ b2,
    const float* __restrict__ w3, const float* __restrict__ b3,
    const float* __restrict__ wa, const float* __restrict__ ba,
    const float* __restrict__ wc, const float* __restrict__ bc,
    float* __restrict__ aggT, float* __restrict__ scores) {
  __shared__ float smem[2 * 4384];
  const int wid = threadIdx.x >> 6;
  const int lane = threadIdx.x & 63;
  const int q = blockIdx.x * 2 + wid;
  const int b = q >> 12;
  float* Xs = smem + wid * 4384;   // [32][68] input; later reused as H2 [32][64]
  float* H1 = Xs + 32 * 68;        // [32][64]
  float* pool = H1 + 32 * 64;      // [128]
  int* idxs = (int*)(pool + 128);  // [32]

  if (lane < 32) idxs[lane] = nidx[q * kNS + lane];
  const float qx = new_xyz[q * 3 + 0];
  const float qy = new_xyz[q * 3 + 1];
  const float qz = new_xyz[q * 3 + 2];
  __syncthreads();

  const float* P = xyz + (size_t)b * kN * 3;
  const float* F = featsT + (size_t)b * kN * kC;
  if (lane < 32) {
    int p = idxs[lane];
    Xs[lane * 68 + 0] = P[p * 3 + 0] - qx;
    Xs[lane * 68 + 1] = P[p * 3 + 1] - qy;
    Xs[lane * 68 + 2] = P[p * 3 + 2] - qz;
  } else {
    Xs[(lane - 32) * 68 + 67] = 0.0f;   // pad column
  }
  for (int j = 0; j < 32; j++) {
    Xs[j * 68 + 3 + lane] = F[(size_t)idxs[j] * kC + lane];
  }
  __syncthreads();

  float w[68];
  // ---- layer 1: 67 -> 64, lane = out channel ----
  {
    const int o = lane;
#pragma unroll
    for (int k = 0; k < 67; k++) w[k] = w1[o * 67 + k];
    w[67] = 0.0f;
    const float bias = b1[o];
    for (int r = 0; r < 32; r++) {
      float acc = bias;
#pragma unroll
      for (int k4 = 0; k4 < 17; k4++) {
        float4 x = *(const float4*)&Xs[r * 68 + k4 * 4];
        acc += x.x * w[k4 * 4 + 0] + x.y * w[k4 * 4 + 1] +
               x.z * w[k4 * 4 + 2] + x.w * w[k4 * 4 + 3];
      }
      H1[r * 64 + o] = fmaxf(acc, 0.0f);
    }
  }
  __syncthreads();
  // ---- layer 2: 64 -> 64, write H2 into Xs region ----
  {
    const int o = lane;
#pragma unroll
    for (int k = 0; k < 64; k++) w[k] = w2[o * 64 + k];
    const float bias = b2[o];
    for (int r = 0; r < 32; r++) {
      float acc = bias;
#pragma unroll
      for (int k4 = 0; k4 < 16; k4++) {
        float4 x = *(const float4*)&H1[r * 64 + k4 * 4];
        acc += x.x * w[k4 * 4 + 0] + x.y * w[k4 * 4 + 1] +
               x.z * w[k4 * 4 + 2] + x.w * w[k4 * 4 + 3];
      }
      Xs[r * 64 + o] = fmaxf(acc, 0.0f);
    }
  }
  __syncthreads();
  // ---- layer 3: 64 -> 128 (2 out channels per lane) + maxpool over rows ----
  {
    const int c = lane;
    float wB[64];
#pragma unroll
    for (int k = 0; k < 64; k++) {
      w[k] = w3[c * 64 + k];
      wB[k] = w3[(c + 64) * 64 + k];
    }
    const float biasA = b3[c];
    const float biasB = b3[c + 64];
    float pa = 0.0f, pb = 0.0f;   // relu folded: max over relu(h) == max(0, max h)
    for (int r = 0; r < 32; r++) {
      float a = biasA, bb = biasB;
#pragma unroll
      for (int k4 = 0; k4 < 16; k4++) {
        float4 x = *(const float4*)&Xs[r * 64 + k4 * 4];
        a  += x.x * w[k4 * 4 + 0] + x.y * w[k4 * 4 + 1] +
              x.z * w[k4 * 4 + 2] + x.w * w[k4 * 4 + 3];
        bb += x.x * wB[k4 * 4 + 0] + x.y * wB[k4 * 4 + 1] +
              x.z * wB[k4 * 4 + 2] + x.w * wB[k4 * 4 + 3];
      }
      pa = fmaxf(pa, a);
      pb = fmaxf(pb, bb);
    }
    pool[c] = pa;
    pool[c + 64] = pb;
  }
  __syncthreads();
  // ---- aggregation 128->128 + relu, confidence 128->1 ----
  {
    const int c = lane;
    float accA = ba[c], accB = ba[c + 64];
#pragma unroll
    for (int k4 = 0; k4 < 32; k4++) {
      float4 pv = *(const float4*)&pool[k4 * 4];
      float4 wva = *(const float4*)&wa[c * 128 + k4 * 4];
      float4 wvb = *(const float4*)&wa[(c + 64) * 128 + k4 * 4];
      accA += pv.x * wva.x + pv.y * wva.y + pv.z * wva.z + pv.w * wva.w;
      accB += pv.x * wvb.x + pv.y * wvb.y + pv.z * wvb.z + pv.w * wvb.w;
    }
    float aggA = fmaxf(accA, 0.0f);
    float aggB = fmaxf(accB, 0.0f);
    aggT[(size_t)q * 128 + c] = aggA;
    aggT[(size_t)q * 128 + 64 + c] = aggB;
    float partial = aggA * wc[c] + aggB * wc[c + 64];
#pragma unroll
    for (int off = 32; off >= 1; off >>= 1) partial += __shfl_xor(partial, off, 64);
    if (lane == 0) scores[q] = partial + bc[0];
  }
}

extern "C" void kernel_launch(void* const* d_in, const int* in_sizes, int n_in,
                              void* d_out, int out_size, void* d_ws, size_t ws_size,
                              hipStream_t stream) {
  const float* xyz   = (const float*)d_in[0];
  const float* feats = (const float*)d_in[1];
  const float* w1 = (const float*)d_in[2];
  const float* b1 = (const float*)d_in[3];
  const float* w2 = (const float*)d_in[4];
  const float* b2 = (const float*)d_in[5];
  const float* w3 = (const float*)d_in[6];
  const float* b3 = (const float*)d_in[7];
  const float* wa = (const float*)d_in[8];
  const float* ba = (const float*)d_in[9];
  const float* wc = (const float*)d_in[10];
  const float* bc = (const float*)d_in[11];

  float* out_new_xyz = (float*)d_out;                               // B*S*3
  float* out_feat    = out_new_xyz + (size_t)kB * kS * 3;           // B*128*S
  float* out_scores  = out_feat + (size_t)kB * 128 * kS;            // B*S

  // ws layout: featsT [0,8MiB), idx [8MiB,9MiB), aggT [9MiB,13MiB).
  // FPS-prep buffers ALIAS the aggT region (consumed before group_mlp writes):
  // pxx/pxy/pxz/pxo 4x128KB, aabb 48KB.
  char* ws = (char*)d_ws;
  float* featsT = (float*)ws;
  int*   idxbuf = (int*)(ws + (size_t)8 * 1024 * 1024);
  float* aggT   = (float*)(ws + (size_t)9 * 1024 * 1024);
  float*    pxx = (float*)(ws + (size_t)9 * 1024 * 1024);
  float*    pxy = (float*)(ws + (size_t)9 * 1024 * 1024 + 128 * 1024);
  float*    pxz = (float*)(ws + (size_t)9 * 1024 * 1024 + 256 * 1024);
  unsigned* pxo = (unsigned*)(ws + (size_t)9 * 1024 * 1024 + 384 * 1024);
  float*   aabb = (float*)(ws + (size_t)9 * 1024 * 1024 + 512 * 1024);

  transpose_kernel<<<dim3(kN / 32, kC / 32, kB), dim3(32, 8, 1), 0, stream>>>(
      feats, featsT, kC, kN);
  fps_prep_kernel<<<dim3(kB), dim3(1024), 0, stream>>>(
      xyz, pxx, pxy, pxz, pxo, aabb);
  fps_kernel<<<dim3(kB), dim3(1024), 0, stream>>>(
      xyz, pxx, pxy, pxz, pxo, aabb, out_new_xyz);
  ball_query_kernel<<<dim3(kB * kS / 4), dim3(256), 0, stream>>>(
      xyz, out_new_xyz, idxbuf);
  group_mlp_kernel<<<dim3(kB * kS / 2), dim3(128), 0, stream>>>(
      xyz, out_new_xyz, featsT, idxbuf,
      w1, b1, w2, b2, w3, b3, wa, ba, wc, bc, aggT, out_scores);
  transpose_kernel<<<dim3(128 / 32, kS / 32, kB), dim3(32, 8, 1), 0, stream>>>(
      aggT, out_feat, kS, 128);
}